// Round 1
// baseline (3761.721 us; speedup 1.0000x reference)
//
#include <hip/hip_runtime.h>
#include <math.h>

namespace {

constexpr int kN1 = 20001;        // NUM_NODES + 1
constexpr int kNE = 1000000;      // NUM_EDGES
constexpr int kNStep = 6;
constexpr int kHid = 128;
constexpr int kB = 64;            // B_SET
constexpr int kNRel2 = 24;        // 2*NUM_REL
constexpr float kEps = 1e-10f;

__device__ __forceinline__ float sig(float x) { return 1.0f / (1.0f + expf(-x)); }

// One block per batch element b (64 blocks, 256 threads). Runs the whole
// 6-step LSTM for that batch row; h/c/x/gates live in LDS.
__global__ __launch_bounds__(256) void lstm_kernel(
    const float* __restrict__ query_emb, const float* __restrict__ w_ih,
    const float* __restrict__ w_hh, const float* __restrict__ b_ih,
    const float* __restrict__ b_hh, const int* __restrict__ r_set,
    float* __restrict__ hidden /* (6,64,128) */) {
  const int b = blockIdx.x;
  const int tid = threadIdx.x;
  __shared__ float xs[kHid], hs[kHid], cs[kHid], gates[4 * kHid];
  if (tid < kHid) { hs[tid] = 0.f; cs[tid] = 0.f; }
  __syncthreads();
  for (int s = 0; s < kNStep; ++s) {
    const int q = (s < kNStep - 1) ? r_set[b] : 12;  // last row uses NUM_REL
    if (tid < kHid) xs[tid] = query_emb[q * kHid + tid];
    __syncthreads();
    for (int j = tid; j < 4 * kHid; j += blockDim.x) {
      const float* wi = &w_ih[j * kHid];
      const float* wh = &w_hh[j * kHid];
      float a = b_ih[j] + b_hh[j];
#pragma unroll 4
      for (int k = 0; k < kHid; ++k) a += xs[k] * wi[k] + hs[k] * wh[k];
      gates[j] = a;
    }
    __syncthreads();
    if (tid < kHid) {
      const float ig = sig(gates[tid]);
      const float fg = sig(gates[kHid + tid]);
      const float gg = tanhf(gates[2 * kHid + tid]);
      const float og = sig(gates[3 * kHid + tid]);
      const float cn = fg * cs[tid] + ig * gg;
      const float hn = og * tanhf(cn);
      cs[tid] = cn;
      hs[tid] = hn;
      hidden[(s * kB + b) * kHid + tid] = hn;
    }
    __syncthreads();
  }
}

// One block per batch b (64 blocks, 128 threads). Computes:
//  attnAll[i][t][b] = softmax_t<=i( dot(h_i, h_t) )
//  weightAll[i][r][b] = softmax_r( h_i @ wl_w.T + wl_b )
__global__ __launch_bounds__(128) void attn_weight_kernel(
    const float* __restrict__ hidden, const float* __restrict__ wl_w,
    const float* __restrict__ wl_b, float* __restrict__ attnAll /* (6,6,64) */,
    float* __restrict__ weightAll /* (6,24,64) */) {
  const int b = blockIdx.x;
  const int tid = threadIdx.x;
  __shared__ float hsm[kNStep][kHid];
  __shared__ float G[kNStep][kNStep];
  __shared__ float logits[kNStep][kNRel2];
  for (int s = 0; s < kNStep; ++s) hsm[s][tid] = hidden[(s * kB + b) * kHid + tid];
  __syncthreads();
  if (tid < 36) {
    const int i = tid / 6, t = tid % 6;
    if (t <= i) {
      float acc = 0.f;
      for (int k = 0; k < kHid; ++k) acc += hsm[i][k] * hsm[t][k];
      G[i][t] = acc;
    }
  }
  for (int p = tid; p < kNStep * kNRel2; p += 128) {
    const int i = p / kNRel2, r = p % kNRel2;
    float acc = wl_b[r];
    for (int k = 0; k < kHid; ++k) acc += hsm[i][k] * wl_w[r * kHid + k];
    logits[i][r] = acc;
  }
  __syncthreads();
  if (tid < kNStep) {
    const int i = tid;
    // attention softmax over t in [0, i]
    float m = G[i][0];
    for (int t = 1; t <= i; ++t) m = fmaxf(m, G[i][t]);
    float ssum = 0.f;
    float ev[kNStep];
    for (int t = 0; t <= i; ++t) { ev[t] = expf(G[i][t] - m); ssum += ev[t]; }
    for (int t = 0; t <= i; ++t) attnAll[(i * kNStep + t) * kB + b] = ev[t] / ssum;
    // relation-weight softmax over 24 types
    float mw = logits[i][0];
    for (int r = 1; r < kNRel2; ++r) mw = fmaxf(mw, logits[i][r]);
    float sw = 0.f;
    float ew[kNRel2];
    for (int r = 0; r < kNRel2; ++r) { ew[r] = expf(logits[i][r] - mw); sw += ew[r]; }
    for (int r = 0; r < kNRel2; ++r) weightAll[(i * kNRel2 + r) * kB + b] = ew[r] / sw;
  }
}

// inp[n][b] = attn[step][0][b]*(n==h_set[b]) + sum_{t=1..step} attn[step][t][b]*outs[t-1][n][b]
// Also zeroes the step's output buffer and colsum.
__global__ __launch_bounds__(256) void inp_zero_kernel(
    const float* __restrict__ attnAll, const int* __restrict__ h_set,
    const float* __restrict__ outs, float* __restrict__ inp,
    float* __restrict__ out_next, float* __restrict__ colsum, int step) {
  const long long total = (long long)kN1 * kB;
  for (long long idx = (long long)blockIdx.x * blockDim.x + threadIdx.x; idx < total;
       idx += (long long)gridDim.x * blockDim.x) {
    const int b = (int)(idx & 63);
    const int n = (int)(idx >> 6);
    float acc = (h_set[b] == n) ? attnAll[(step * kNStep) * kB + b] : 0.f;
    for (int t = 1; t <= step; ++t)
      acc += attnAll[(step * kNStep + t) * kB + b] *
             outs[(long long)(t - 1) * kN1 * kB + idx];
    inp[idx] = acc;
    out_next[idx] = 0.f;
  }
  if (blockIdx.x == 0 && threadIdx.x < kB) colsum[threadIdx.x] = 0.f;
}

// One wave per group of edges (grid-stride). Lane b handles batch column b:
// out[node_out[e]][b] += inp[node_in[e]][b] * weight[edge_type[e]][b]
__global__ __launch_bounds__(256) void scatter_kernel(
    const float* __restrict__ inp, const float* __restrict__ weight /* (24,64) */,
    const int* __restrict__ nin, const int* __restrict__ nout,
    const int* __restrict__ etype, float* __restrict__ out,
    float* __restrict__ colsum) {
  const int lane = threadIdx.x & 63;
  const int wave = blockIdx.x * (blockDim.x >> 6) + (threadIdx.x >> 6);
  const int nwave = gridDim.x * (blockDim.x >> 6);
  __shared__ float wsm[kNRel2 * kB];
  for (int j = threadIdx.x; j < kNRel2 * kB; j += blockDim.x) wsm[j] = weight[j];
  __syncthreads();
  float csum = 0.f;
  for (int e = wave; e < kNE; e += nwave) {
    const int a = nin[e];
    const int o = nout[e];
    const int t = etype[e];
    const float v = inp[(long long)a * kB + lane] * wsm[t * kB + lane];
    unsafeAtomicAdd(&out[(long long)o * kB + lane], v);
    csum += v;
  }
  unsafeAtomicAdd(&colsum[lane], csum);
}

__global__ __launch_bounds__(256) void normalize_kernel(
    float* __restrict__ out, const float* __restrict__ colsum) {
  const long long total = (long long)kN1 * kB;
  for (long long idx = (long long)blockIdx.x * blockDim.x + threadIdx.x; idx < total;
       idx += (long long)gridDim.x * blockDim.x) {
    out[idx] /= fmaxf(colsum[idx & 63], kEps);
  }
}

__global__ __launch_bounds__(256) void score_kernel(
    const float* __restrict__ outLast, const int* __restrict__ t_index,
    const int* __restrict__ hr_inverse, const float* __restrict__ lin_w,
    const float* __restrict__ lin_b, float* __restrict__ out, int n) {
  const int i = blockIdx.x * blockDim.x + threadIdx.x;
  if (i < n) {
    const int node = t_index[i];
    const int b = hr_inverse[i];
    out[i] = outLast[(long long)node * kB + b] * lin_w[0] + lin_b[0];
  }
}

}  // namespace

extern "C" void kernel_launch(void* const* d_in, const int* in_sizes, int n_in,
                              void* d_out, int out_size, void* d_ws, size_t ws_size,
                              hipStream_t stream) {
  const float* query_emb = (const float*)d_in[0];
  const float* w_ih = (const float*)d_in[1];
  const float* w_hh = (const float*)d_in[2];
  const float* b_ih = (const float*)d_in[3];
  const float* b_hh = (const float*)d_in[4];
  const float* wl_w = (const float*)d_in[5];
  const float* wl_b = (const float*)d_in[6];
  const float* lin_w = (const float*)d_in[7];
  const float* lin_b = (const float*)d_in[8];
  const int* edge_index = (const int*)d_in[9];
  const int* edge_type = (const int*)d_in[10];
  const int* h_set = (const int*)d_in[11];
  const int* r_set = (const int*)d_in[12];
  const int* t_index = (const int*)d_in[13];
  const int* hr_inverse = (const int*)d_in[14];
  float* out = (float*)d_out;

  // Workspace layout (floats): total ~9.03M floats (~36.1 MB)
  float* ws = (float*)d_ws;
  float* hidden = ws;                              // 6*64*128 = 49152
  float* attnAll = hidden + 6 * kB * kHid;         // 6*6*64 = 2304
  float* weightAll = attnAll + 6 * 6 * kB;         // 6*24*64 = 9216
  float* colsum = weightAll + 6 * kNRel2 * kB;     // 64
  float* inp = colsum + kB;                        // N1*64
  float* outs = inp + (long long)kN1 * kB;         // 6 * N1*64

  const int* nin = edge_index;            // edge_index[0]
  const int* nout = edge_index + kNE;     // edge_index[1]

  lstm_kernel<<<kB, 256, 0, stream>>>(query_emb, w_ih, w_hh, b_ih, b_hh, r_set, hidden);
  attn_weight_kernel<<<kB, 128, 0, stream>>>(hidden, wl_w, wl_b, attnAll, weightAll);

  for (int i = 0; i < kNStep; ++i) {
    float* out_i = outs + (long long)i * kN1 * kB;
    inp_zero_kernel<<<2048, 256, 0, stream>>>(attnAll, h_set, outs, inp, out_i, colsum, i);
    scatter_kernel<<<4096, 256, 0, stream>>>(inp, weightAll + i * kNRel2 * kB, nin, nout,
                                             edge_type, out_i, colsum);
    normalize_kernel<<<2048, 256, 0, stream>>>(out_i, colsum);
  }

  score_kernel<<<(out_size + 255) / 256, 256, 0, stream>>>(
      outs + 5LL * kN1 * kB, t_index, hr_inverse, lin_w, lin_b, out, out_size);
}

// Round 2
// 1162.334 us; speedup vs baseline: 3.2364x; 3.2364x over previous
//
#include <hip/hip_runtime.h>
#include <math.h>

namespace {

constexpr int kN1 = 20001;        // NUM_NODES + 1
constexpr int kNE = 1000000;      // NUM_EDGES
constexpr int kNStep = 6;
constexpr int kHid = 128;
constexpr int kB = 64;            // B_SET
constexpr int kNRel2 = 24;        // 2*NUM_REL
constexpr float kEps = 1e-10f;

__device__ __forceinline__ float sig(float x) { return 1.0f / (1.0f + expf(-x)); }

// ---------------- tiny front-end (unchanged from round 1) ----------------

__global__ __launch_bounds__(256) void lstm_kernel(
    const float* __restrict__ query_emb, const float* __restrict__ w_ih,
    const float* __restrict__ w_hh, const float* __restrict__ b_ih,
    const float* __restrict__ b_hh, const int* __restrict__ r_set,
    float* __restrict__ hidden /* (6,64,128) */) {
  const int b = blockIdx.x;
  const int tid = threadIdx.x;
  __shared__ float xs[kHid], hs[kHid], cs[kHid], gates[4 * kHid];
  if (tid < kHid) { hs[tid] = 0.f; cs[tid] = 0.f; }
  __syncthreads();
  for (int s = 0; s < kNStep; ++s) {
    const int q = (s < kNStep - 1) ? r_set[b] : 12;
    if (tid < kHid) xs[tid] = query_emb[q * kHid + tid];
    __syncthreads();
    for (int j = tid; j < 4 * kHid; j += blockDim.x) {
      const float* wi = &w_ih[j * kHid];
      const float* wh = &w_hh[j * kHid];
      float a = b_ih[j] + b_hh[j];
#pragma unroll 4
      for (int k = 0; k < kHid; ++k) a += xs[k] * wi[k] + hs[k] * wh[k];
      gates[j] = a;
    }
    __syncthreads();
    if (tid < kHid) {
      const float ig = sig(gates[tid]);
      const float fg = sig(gates[kHid + tid]);
      const float gg = tanhf(gates[2 * kHid + tid]);
      const float og = sig(gates[3 * kHid + tid]);
      const float cn = fg * cs[tid] + ig * gg;
      const float hn = og * tanhf(cn);
      cs[tid] = cn;
      hs[tid] = hn;
      hidden[(s * kB + b) * kHid + tid] = hn;
    }
    __syncthreads();
  }
}

__global__ __launch_bounds__(128) void attn_weight_kernel(
    const float* __restrict__ hidden, const float* __restrict__ wl_w,
    const float* __restrict__ wl_b, float* __restrict__ attnAll /* (6,6,64) */,
    float* __restrict__ weightAll /* (6,24,64) */) {
  const int b = blockIdx.x;
  const int tid = threadIdx.x;
  __shared__ float hsm[kNStep][kHid];
  __shared__ float G[kNStep][kNStep];
  __shared__ float logits[kNStep][kNRel2];
  for (int s = 0; s < kNStep; ++s) hsm[s][tid] = hidden[(s * kB + b) * kHid + tid];
  __syncthreads();
  if (tid < 36) {
    const int i = tid / 6, t = tid % 6;
    if (t <= i) {
      float acc = 0.f;
      for (int k = 0; k < kHid; ++k) acc += hsm[i][k] * hsm[t][k];
      G[i][t] = acc;
    }
  }
  for (int p = tid; p < kNStep * kNRel2; p += 128) {
    const int i = p / kNRel2, r = p % kNRel2;
    float acc = wl_b[r];
    for (int k = 0; k < kHid; ++k) acc += hsm[i][k] * wl_w[r * kHid + k];
    logits[i][r] = acc;
  }
  __syncthreads();
  if (tid < kNStep) {
    const int i = tid;
    float m = G[i][0];
    for (int t = 1; t <= i; ++t) m = fmaxf(m, G[i][t]);
    float ssum = 0.f;
    float ev[kNStep];
    for (int t = 0; t <= i; ++t) { ev[t] = expf(G[i][t] - m); ssum += ev[t]; }
    for (int t = 0; t <= i; ++t) attnAll[(i * kNStep + t) * kB + b] = ev[t] / ssum;
    float mw = logits[i][0];
    for (int r = 1; r < kNRel2; ++r) mw = fmaxf(mw, logits[i][r]);
    float sw = 0.f;
    float ew[kNRel2];
    for (int r = 0; r < kNRel2; ++r) { ew[r] = expf(logits[i][r] - mw); sw += ew[r]; }
    for (int r = 0; r < kNRel2; ++r) weightAll[(i * kNRel2 + r) * kB + b] = ew[r] / sw;
  }
}

// ---------------- edge preprocessing (once per launch) ----------------

__global__ __launch_bounds__(256) void zero_kernel(int* __restrict__ counts,
                                                   float* __restrict__ colsumAll) {
  const int i = blockIdx.x * blockDim.x + threadIdx.x;
  if (i < kN1) counts[i] = 0;
  if (i < kNStep * kB) colsumAll[i] = 0.f;
}

__global__ __launch_bounds__(256) void hist_kernel(const int* __restrict__ nout,
                                                   int* __restrict__ counts) {
  for (int e = blockIdx.x * blockDim.x + threadIdx.x; e < kNE;
       e += gridDim.x * blockDim.x)
    atomicAdd(&counts[nout[e]], 1);
}

__global__ __launch_bounds__(1024) void scan_kernel(const int* __restrict__ counts,
                                                    int* __restrict__ offsets,
                                                    int* __restrict__ cursor) {
  __shared__ int part[1024];
  const int tid = threadIdx.x;
  const int chunk = (kN1 + 1023) / 1024;  // 20
  const int beg = tid * chunk;
  const int end = min(beg + chunk, kN1);
  int s = 0;
  for (int i = beg; i < end; ++i) s += counts[i];
  part[tid] = s;
  __syncthreads();
  for (int off = 1; off < 1024; off <<= 1) {
    const int v = (tid >= off) ? part[tid - off] : 0;
    __syncthreads();
    part[tid] += v;
    __syncthreads();
  }
  int run = part[tid] - s;  // exclusive prefix of this chunk
  for (int i = beg; i < end; ++i) {
    offsets[i] = run;
    cursor[i] = run;
    run += counts[i];
  }
  if (tid == 1023) offsets[kN1] = part[1023];
}

__global__ __launch_bounds__(256) void permute_kernel(
    const int* __restrict__ nin, const int* __restrict__ nout,
    const int* __restrict__ etype, int* __restrict__ cursor,
    unsigned* __restrict__ packed) {
  for (int e = blockIdx.x * blockDim.x + threadIdx.x; e < kNE;
       e += gridDim.x * blockDim.x) {
    const int d = nout[e];
    const int pos = atomicAdd(&cursor[d], 1);
    packed[pos] = (unsigned)nin[e] | ((unsigned)etype[e] << 15);
  }
}

// ---------------- per-step kernels ----------------

// inp[n][b] = attn[step][0][b]*(n==h_set[b])
//           + sum_{t=1..step} attn[step][t][b]/max(colsum[t-1][b],eps) * outs[t-1][n][b]
__global__ __launch_bounds__(256) void inp_kernel(
    const float* __restrict__ attnAll, const float* __restrict__ colsumAll,
    const int* __restrict__ h_set, const float* __restrict__ outs,
    float* __restrict__ inp, int step) {
  __shared__ float coef[kNStep][kB];
  __shared__ int hsm[kB];
  const int tid = threadIdx.x;
  if (tid < kNStep * kB) {
    const int t = tid >> 6, b = tid & 63;
    if (t == 0)
      coef[0][b] = attnAll[(step * kNStep) * kB + b];
    else if (t <= step)
      coef[t][b] = attnAll[(step * kNStep + t) * kB + b] /
                   fmaxf(colsumAll[(t - 1) * kB + b], kEps);
  }
  if (tid < kB) hsm[tid] = h_set[tid];
  __syncthreads();
  const long long total = (long long)kN1 * kB;
  for (long long idx = (long long)blockIdx.x * blockDim.x + threadIdx.x; idx < total;
       idx += (long long)gridDim.x * blockDim.x) {
    const int b = (int)(idx & 63);
    const int n = (int)(idx >> 6);
    float acc = (hsm[b] == n) ? coef[0][b] : 0.f;
    for (int t = 1; t <= step; ++t)
      acc += coef[t][b] * outs[(long long)(t - 1) * kN1 * kB + idx];
    inp[idx] = acc;
  }
}

// One wave per destination node: walk its (sorted) edge bin, accumulate the
// 64-wide row in registers, single store. No float atomics on out.
__global__ __launch_bounds__(256) void gather_edges_kernel(
    const float* __restrict__ inp, const float* __restrict__ weight /* (24,64) */,
    const unsigned* __restrict__ packed, const int* __restrict__ offsets,
    float* __restrict__ out, float* __restrict__ colsum) {
  __shared__ float wsm[kNRel2 * kB];
  __shared__ float red[4][kB];
  const int tid = threadIdx.x;
  const int lane = tid & 63;
  const int wid = tid >> 6;
  for (int j = tid; j < kNRel2 * kB; j += blockDim.x) wsm[j] = weight[j];
  __syncthreads();
  const int node = blockIdx.x * 4 + wid;
  float acc0 = 0.f, acc1 = 0.f;
  if (node < kN1) {
    const int beg = offsets[node];
    const int end = offsets[node + 1];
    int e = beg;
    for (; e + 1 < end; e += 2) {
      const unsigned p0 = packed[e], p1 = packed[e + 1];
      acc0 += inp[(long long)(p0 & 0x7fffu) * kB + lane] * wsm[(p0 >> 15) * kB + lane];
      acc1 += inp[(long long)(p1 & 0x7fffu) * kB + lane] * wsm[(p1 >> 15) * kB + lane];
    }
    if (e < end) {
      const unsigned p0 = packed[e];
      acc0 += inp[(long long)(p0 & 0x7fffu) * kB + lane] * wsm[(p0 >> 15) * kB + lane];
    }
    out[(long long)node * kB + lane] = acc0 + acc1;
  }
  red[wid][lane] = acc0 + acc1;
  __syncthreads();
  if (wid == 0) {
    const float s = red[0][lane] + red[1][lane] + red[2][lane] + red[3][lane];
    unsafeAtomicAdd(&colsum[lane], s);
  }
}

__global__ __launch_bounds__(256) void score_kernel(
    const float* __restrict__ outLast, const float* __restrict__ colsumLast,
    const int* __restrict__ t_index, const int* __restrict__ hr_inverse,
    const float* __restrict__ lin_w, const float* __restrict__ lin_b,
    float* __restrict__ out, int n) {
  const int i = blockIdx.x * blockDim.x + threadIdx.x;
  if (i < n) {
    const int node = t_index[i];
    const int b = hr_inverse[i];
    const float v = outLast[(long long)node * kB + b] / fmaxf(colsumLast[b], kEps);
    out[i] = v * lin_w[0] + lin_b[0];
  }
}

// ---------------- round-1 fallback (float-atomic scatter) ----------------

__global__ __launch_bounds__(256) void inp_zero_kernel(
    const float* __restrict__ attnAll, const int* __restrict__ h_set,
    const float* __restrict__ outs, float* __restrict__ inp,
    float* __restrict__ out_next, float* __restrict__ colsum, int step) {
  const long long total = (long long)kN1 * kB;
  for (long long idx = (long long)blockIdx.x * blockDim.x + threadIdx.x; idx < total;
       idx += (long long)gridDim.x * blockDim.x) {
    const int b = (int)(idx & 63);
    const int n = (int)(idx >> 6);
    float acc = (h_set[b] == n) ? attnAll[(step * kNStep) * kB + b] : 0.f;
    for (int t = 1; t <= step; ++t)
      acc += attnAll[(step * kNStep + t) * kB + b] *
             outs[(long long)(t - 1) * kN1 * kB + idx];
    inp[idx] = acc;
    out_next[idx] = 0.f;
  }
  if (blockIdx.x == 0 && threadIdx.x < kB) colsum[threadIdx.x] = 0.f;
}

__global__ __launch_bounds__(256) void scatter_kernel(
    const float* __restrict__ inp, const float* __restrict__ weight,
    const int* __restrict__ nin, const int* __restrict__ nout,
    const int* __restrict__ etype, float* __restrict__ out,
    float* __restrict__ colsum) {
  const int lane = threadIdx.x & 63;
  const int wave = blockIdx.x * (blockDim.x >> 6) + (threadIdx.x >> 6);
  const int nwave = gridDim.x * (blockDim.x >> 6);
  __shared__ float wsm[kNRel2 * kB];
  for (int j = threadIdx.x; j < kNRel2 * kB; j += blockDim.x) wsm[j] = weight[j];
  __syncthreads();
  float csum = 0.f;
  for (int e = wave; e < kNE; e += nwave) {
    const float v = inp[(long long)nin[e] * kB + lane] * wsm[etype[e] * kB + lane];
    unsafeAtomicAdd(&out[(long long)nout[e] * kB + lane], v);
    csum += v;
  }
  unsafeAtomicAdd(&colsum[lane], csum);
}

__global__ __launch_bounds__(256) void normalize_kernel(
    float* __restrict__ out, const float* __restrict__ colsum) {
  const long long total = (long long)kN1 * kB;
  for (long long idx = (long long)blockIdx.x * blockDim.x + threadIdx.x; idx < total;
       idx += (long long)gridDim.x * blockDim.x)
    out[idx] /= fmaxf(colsum[idx & 63], kEps);
}

__global__ __launch_bounds__(256) void score_kernel_norm(
    const float* __restrict__ outLast, const int* __restrict__ t_index,
    const int* __restrict__ hr_inverse, const float* __restrict__ lin_w,
    const float* __restrict__ lin_b, float* __restrict__ out, int n) {
  const int i = blockIdx.x * blockDim.x + threadIdx.x;
  if (i < n) {
    out[i] = outLast[(long long)t_index[i] * kB + hr_inverse[i]] * lin_w[0] + lin_b[0];
  }
}

}  // namespace

extern "C" void kernel_launch(void* const* d_in, const int* in_sizes, int n_in,
                              void* d_out, int out_size, void* d_ws, size_t ws_size,
                              hipStream_t stream) {
  const float* query_emb = (const float*)d_in[0];
  const float* w_ih = (const float*)d_in[1];
  const float* w_hh = (const float*)d_in[2];
  const float* b_ih = (const float*)d_in[3];
  const float* b_hh = (const float*)d_in[4];
  const float* wl_w = (const float*)d_in[5];
  const float* wl_b = (const float*)d_in[6];
  const float* lin_w = (const float*)d_in[7];
  const float* lin_b = (const float*)d_in[8];
  const int* edge_index = (const int*)d_in[9];
  const int* edge_type = (const int*)d_in[10];
  const int* h_set = (const int*)d_in[11];
  const int* r_set = (const int*)d_in[12];
  const int* t_index = (const int*)d_in[13];
  const int* hr_inverse = (const int*)d_in[14];
  float* out = (float*)d_out;

  const int* nin = edge_index;
  const int* nout = edge_index + kNE;

  // ---- workspace layout ----
  float* ws = (float*)d_ws;
  float* hidden = ws;                                   // 6*64*128
  float* attnAll = hidden + kNStep * kB * kHid;         // 6*6*64
  float* weightAll = attnAll + kNStep * kNStep * kB;    // 6*24*64
  float* colsumAll = weightAll + kNStep * kNRel2 * kB;  // 6*64
  float* inp = colsumAll + kNStep * kB;                 // N1*64
  float* outs = inp + (long long)kN1 * kB;              // 6*N1*64
  float* tail = outs + (long long)kNStep * kN1 * kB;
  int* counts = (int*)tail;                             // N1
  int* offsets = counts + kN1;                          // N1+1
  int* cursor = offsets + kN1 + 1;                      // N1
  unsigned* packed = (unsigned*)(cursor + kN1);         // NE
  const size_t needed = (size_t)((char*)(packed + kNE) - (char*)d_ws);

  lstm_kernel<<<kB, 256, 0, stream>>>(query_emb, w_ih, w_hh, b_ih, b_hh, r_set, hidden);
  attn_weight_kernel<<<kB, 128, 0, stream>>>(hidden, wl_w, wl_b, attnAll, weightAll);

  if (ws_size >= needed) {
    // ---- sorted-gather path (no float atomics) ----
    zero_kernel<<<(kN1 + 255) / 256, 256, 0, stream>>>(counts, colsumAll);
    hist_kernel<<<1024, 256, 0, stream>>>(nout, counts);
    scan_kernel<<<1, 1024, 0, stream>>>(counts, offsets, cursor);
    permute_kernel<<<1024, 256, 0, stream>>>(nin, nout, edge_type, cursor, packed);

    for (int i = 0; i < kNStep; ++i) {
      float* out_i = outs + (long long)i * kN1 * kB;
      inp_kernel<<<2048, 256, 0, stream>>>(attnAll, colsumAll, h_set, outs, inp, i);
      gather_edges_kernel<<<(kN1 + 3) / 4, 256, 0, stream>>>(
          inp, weightAll + i * kNRel2 * kB, packed, offsets, out_i,
          colsumAll + i * kB);
    }
    score_kernel<<<(out_size + 255) / 256, 256, 0, stream>>>(
        outs + 5LL * kN1 * kB, colsumAll + 5 * kB, t_index, hr_inverse, lin_w, lin_b,
        out, out_size);
  } else {
    // ---- fallback: round-1 atomic path ----
    float* colsum = colsumAll;
    for (int i = 0; i < kNStep; ++i) {
      float* out_i = outs + (long long)i * kN1 * kB;
      inp_zero_kernel<<<2048, 256, 0, stream>>>(attnAll, h_set, outs, inp, out_i,
                                                colsum, i);
      scatter_kernel<<<4096, 256, 0, stream>>>(inp, weightAll + i * kNRel2 * kB, nin,
                                               nout, edge_type, out_i, colsum);
      normalize_kernel<<<2048, 256, 0, stream>>>(out_i, colsum);
    }
    score_kernel_norm<<<(out_size + 255) / 256, 256, 0, stream>>>(
        outs + 5LL * kN1 * kB, t_index, hr_inverse, lin_w, lin_b, out, out_size);
  }
}

// Round 3
// 1100.474 us; speedup vs baseline: 3.4183x; 1.0562x over previous
//
#include <hip/hip_runtime.h>
#include <hip/hip_fp16.h>
#include <math.h>

namespace {

constexpr int kN1 = 20001;        // NUM_NODES + 1
constexpr int kNE = 1000000;      // NUM_EDGES
constexpr int kNStep = 6;
constexpr int kHid = 128;
constexpr int kB = 64;            // B_SET
constexpr int kNRel2 = 24;        // 2*NUM_REL
constexpr float kEps = 1e-10f;

__device__ __forceinline__ float sig(float x) { return 1.0f / (1.0f + expf(-x)); }

// ---------------- tiny front-end ----------------

__global__ __launch_bounds__(256) void lstm_kernel(
    const float* __restrict__ query_emb, const float* __restrict__ w_ih,
    const float* __restrict__ w_hh, const float* __restrict__ b_ih,
    const float* __restrict__ b_hh, const int* __restrict__ r_set,
    float* __restrict__ hidden /* (6,64,128) */) {
  const int b = blockIdx.x;
  const int tid = threadIdx.x;
  __shared__ float xs[kHid], hs[kHid], cs[kHid], gates[4 * kHid];
  if (tid < kHid) { hs[tid] = 0.f; cs[tid] = 0.f; }
  __syncthreads();
  for (int s = 0; s < kNStep; ++s) {
    const int q = (s < kNStep - 1) ? r_set[b] : 12;
    if (tid < kHid) xs[tid] = query_emb[q * kHid + tid];
    __syncthreads();
    for (int j = tid; j < 4 * kHid; j += blockDim.x) {
      const float* wi = &w_ih[j * kHid];
      const float* wh = &w_hh[j * kHid];
      float a = b_ih[j] + b_hh[j];
#pragma unroll 4
      for (int k = 0; k < kHid; ++k) a += xs[k] * wi[k] + hs[k] * wh[k];
      gates[j] = a;
    }
    __syncthreads();
    if (tid < kHid) {
      const float ig = sig(gates[tid]);
      const float fg = sig(gates[kHid + tid]);
      const float gg = tanhf(gates[2 * kHid + tid]);
      const float og = sig(gates[3 * kHid + tid]);
      const float cn = fg * cs[tid] + ig * gg;
      const float hn = og * tanhf(cn);
      cs[tid] = cn;
      hs[tid] = hn;
      hidden[(s * kB + b) * kHid + tid] = hn;
    }
    __syncthreads();
  }
}

__global__ __launch_bounds__(128) void attn_weight_kernel(
    const float* __restrict__ hidden, const float* __restrict__ wl_w,
    const float* __restrict__ wl_b, float* __restrict__ attnAll /* (6,6,64) */,
    float* __restrict__ weightAll /* (6,24,64) */) {
  const int b = blockIdx.x;
  const int tid = threadIdx.x;
  __shared__ float hsm[kNStep][kHid];
  __shared__ float G[kNStep][kNStep];
  __shared__ float logits[kNStep][kNRel2];
  for (int s = 0; s < kNStep; ++s) hsm[s][tid] = hidden[(s * kB + b) * kHid + tid];
  __syncthreads();
  if (tid < 36) {
    const int i = tid / 6, t = tid % 6;
    if (t <= i) {
      float acc = 0.f;
      for (int k = 0; k < kHid; ++k) acc += hsm[i][k] * hsm[t][k];
      G[i][t] = acc;
    }
  }
  for (int p = tid; p < kNStep * kNRel2; p += 128) {
    const int i = p / kNRel2, r = p % kNRel2;
    float acc = wl_b[r];
    for (int k = 0; k < kHid; ++k) acc += hsm[i][k] * wl_w[r * kHid + k];
    logits[i][r] = acc;
  }
  __syncthreads();
  if (tid < kNStep) {
    const int i = tid;
    float m = G[i][0];
    for (int t = 1; t <= i; ++t) m = fmaxf(m, G[i][t]);
    float ssum = 0.f;
    float ev[kNStep];
    for (int t = 0; t <= i; ++t) { ev[t] = expf(G[i][t] - m); ssum += ev[t]; }
    for (int t = 0; t <= i; ++t) attnAll[(i * kNStep + t) * kB + b] = ev[t] / ssum;
    float mw = logits[i][0];
    for (int r = 1; r < kNRel2; ++r) mw = fmaxf(mw, logits[i][r]);
    float sw = 0.f;
    float ew[kNRel2];
    for (int r = 0; r < kNRel2; ++r) { ew[r] = expf(logits[i][r] - mw); sw += ew[r]; }
    for (int r = 0; r < kNRel2; ++r) weightAll[(i * kNRel2 + r) * kB + b] = ew[r] / sw;
  }
}

// ---------------- edge preprocessing (once per launch) ----------------

__global__ __launch_bounds__(256) void zero_kernel(int* __restrict__ counts,
                                                   float* __restrict__ colsumAll) {
  const int i = blockIdx.x * blockDim.x + threadIdx.x;
  if (i < kN1) counts[i] = 0;
  if (i < kNStep * kB) colsumAll[i] = 0.f;
}

__global__ __launch_bounds__(256) void hist_kernel(const int* __restrict__ nout,
                                                   int* __restrict__ counts) {
  for (int e = blockIdx.x * blockDim.x + threadIdx.x; e < kNE;
       e += gridDim.x * blockDim.x)
    atomicAdd(&counts[nout[e]], 1);
}

__global__ __launch_bounds__(1024) void scan_kernel(const int* __restrict__ counts,
                                                    int* __restrict__ offsets,
                                                    int* __restrict__ cursor) {
  __shared__ int part[1024];
  const int tid = threadIdx.x;
  const int chunk = (kN1 + 1023) / 1024;  // 20
  const int beg = tid * chunk;
  const int end = min(beg + chunk, kN1);
  int s = 0;
  for (int i = beg; i < end; ++i) s += counts[i];
  part[tid] = s;
  __syncthreads();
  for (int off = 1; off < 1024; off <<= 1) {
    const int v = (tid >= off) ? part[tid - off] : 0;
    __syncthreads();
    part[tid] += v;
    __syncthreads();
  }
  int run = part[tid] - s;  // exclusive prefix of this chunk
  for (int i = beg; i < end; ++i) {
    offsets[i] = run;
    cursor[i] = run;
    run += counts[i];
  }
  if (tid == 1023) offsets[kN1] = part[1023];
}

__global__ __launch_bounds__(256) void permute_kernel(
    const int* __restrict__ nin, const int* __restrict__ nout,
    const int* __restrict__ etype, int* __restrict__ cursor,
    unsigned* __restrict__ packed) {
  for (int e = blockIdx.x * blockDim.x + threadIdx.x; e < kNE;
       e += gridDim.x * blockDim.x) {
    const int d = nout[e];
    const int pos = atomicAdd(&cursor[d], 1);
    packed[pos] = (unsigned)nin[e] | ((unsigned)etype[e] << 15);
  }
}

// ---------------- per-step kernels ----------------

// inp (fp16) [n][b] = attn[step][0][b]*(n==h_set[b])
//   + sum_{t=1..step} attn[step][t][b]/max(colsum[t-1][b],eps) * outs[t-1][n][b]
__global__ __launch_bounds__(256) void inp_kernel(
    const float* __restrict__ attnAll, const float* __restrict__ colsumAll,
    const int* __restrict__ h_set, const float* __restrict__ outs,
    __half* __restrict__ inp, int step) {
  __shared__ float coef[kNStep][kB];
  __shared__ int hsm[kB];
  const int tid = threadIdx.x;
  if (tid < kNStep * kB) {
    const int t = tid >> 6, b = tid & 63;
    if (t == 0)
      coef[0][b] = attnAll[(step * kNStep) * kB + b];
    else if (t <= step)
      coef[t][b] = attnAll[(step * kNStep + t) * kB + b] /
                   fmaxf(colsumAll[(t - 1) * kB + b], kEps);
  }
  if (tid < kB) hsm[tid] = h_set[tid];
  __syncthreads();
  const long long total = (long long)kN1 * kB;
  for (long long idx = (long long)blockIdx.x * blockDim.x + threadIdx.x; idx < total;
       idx += (long long)gridDim.x * blockDim.x) {
    const int b = (int)(idx & 63);
    const int n = (int)(idx >> 6);
    float acc = (hsm[b] == n) ? coef[0][b] : 0.f;
    for (int t = 1; t <= step; ++t)
      acc += coef[t][b] * outs[(long long)(t - 1) * kN1 * kB + idx];
    inp[idx] = __float2half(acc);
  }
}

// One wave per destination node: walk its edge bin with 4 independent
// accumulators (MLP), fp16 L2-resident inp table, single f32 store.
__global__ __launch_bounds__(256) void gather_edges_kernel(
    const __half* __restrict__ inp, const float* __restrict__ weight /* (24,64) */,
    const unsigned* __restrict__ packed, const int* __restrict__ offsets,
    float* __restrict__ out, float* __restrict__ colsum) {
  __shared__ float wsm[kNRel2 * kB];
  __shared__ float red[4][kB];
  const int tid = threadIdx.x;
  const int lane = tid & 63;
  const int wid = tid >> 6;
  for (int j = tid; j < kNRel2 * kB; j += blockDim.x) wsm[j] = weight[j];
  __syncthreads();
  const int node = blockIdx.x * 4 + wid;
  float a0 = 0.f, a1 = 0.f, a2 = 0.f, a3 = 0.f;
  float s = 0.f;
  if (node < kN1) {
    const int beg = offsets[node];
    const int end = offsets[node + 1];
    int e = beg;
    for (; e + 3 < end; e += 4) {
      const unsigned p0 = packed[e], p1 = packed[e + 1];
      const unsigned p2 = packed[e + 2], p3 = packed[e + 3];
      const float v0 = __half2float(inp[(p0 & 0x7fffu) * kB + lane]);
      const float v1 = __half2float(inp[(p1 & 0x7fffu) * kB + lane]);
      const float v2 = __half2float(inp[(p2 & 0x7fffu) * kB + lane]);
      const float v3 = __half2float(inp[(p3 & 0x7fffu) * kB + lane]);
      a0 += v0 * wsm[(p0 >> 15) * kB + lane];
      a1 += v1 * wsm[(p1 >> 15) * kB + lane];
      a2 += v2 * wsm[(p2 >> 15) * kB + lane];
      a3 += v3 * wsm[(p3 >> 15) * kB + lane];
    }
    for (; e < end; ++e) {
      const unsigned p0 = packed[e];
      a0 += __half2float(inp[(p0 & 0x7fffu) * kB + lane]) * wsm[(p0 >> 15) * kB + lane];
    }
    s = (a0 + a1) + (a2 + a3);
    out[(long long)node * kB + lane] = s;
  }
  red[wid][lane] = s;
  __syncthreads();
  if (wid == 0) {
    const float r = red[0][lane] + red[1][lane] + red[2][lane] + red[3][lane];
    unsafeAtomicAdd(&colsum[lane], r);
  }
}

__global__ __launch_bounds__(256) void score_kernel(
    const float* __restrict__ outLast, const float* __restrict__ colsumLast,
    const int* __restrict__ t_index, const int* __restrict__ hr_inverse,
    const float* __restrict__ lin_w, const float* __restrict__ lin_b,
    float* __restrict__ out, int n) {
  const int i = blockIdx.x * blockDim.x + threadIdx.x;
  if (i < n) {
    const int node = t_index[i];
    const int b = hr_inverse[i];
    const float v = outLast[(long long)node * kB + b] / fmaxf(colsumLast[b], kEps);
    out[i] = v * lin_w[0] + lin_b[0];
  }
}

// ---------------- fallback (float-atomic scatter, round-1 path) ----------------

__global__ __launch_bounds__(256) void inp_zero_kernel(
    const float* __restrict__ attnAll, const int* __restrict__ h_set,
    const float* __restrict__ outs, float* __restrict__ inp,
    float* __restrict__ out_next, float* __restrict__ colsum, int step) {
  const long long total = (long long)kN1 * kB;
  for (long long idx = (long long)blockIdx.x * blockDim.x + threadIdx.x; idx < total;
       idx += (long long)gridDim.x * blockDim.x) {
    const int b = (int)(idx & 63);
    const int n = (int)(idx >> 6);
    float acc = (h_set[b] == n) ? attnAll[(step * kNStep) * kB + b] : 0.f;
    for (int t = 1; t <= step; ++t)
      acc += attnAll[(step * kNStep + t) * kB + b] *
             outs[(long long)(t - 1) * kN1 * kB + idx];
    inp[idx] = acc;
    out_next[idx] = 0.f;
  }
  if (blockIdx.x == 0 && threadIdx.x < kB) colsum[threadIdx.x] = 0.f;
}

__global__ __launch_bounds__(256) void scatter_kernel(
    const float* __restrict__ inp, const float* __restrict__ weight,
    const int* __restrict__ nin, const int* __restrict__ nout,
    const int* __restrict__ etype, float* __restrict__ out,
    float* __restrict__ colsum) {
  const int lane = threadIdx.x & 63;
  const int wave = blockIdx.x * (blockDim.x >> 6) + (threadIdx.x >> 6);
  const int nwave = gridDim.x * (blockDim.x >> 6);
  __shared__ float wsm[kNRel2 * kB];
  for (int j = threadIdx.x; j < kNRel2 * kB; j += blockDim.x) wsm[j] = weight[j];
  __syncthreads();
  float csum = 0.f;
  for (int e = wave; e < kNE; e += nwave) {
    const float v = inp[(long long)nin[e] * kB + lane] * wsm[etype[e] * kB + lane];
    unsafeAtomicAdd(&out[(long long)nout[e] * kB + lane], v);
    csum += v;
  }
  unsafeAtomicAdd(&colsum[lane], csum);
}

__global__ __launch_bounds__(256) void normalize_kernel(
    float* __restrict__ out, const float* __restrict__ colsum) {
  const long long total = (long long)kN1 * kB;
  for (long long idx = (long long)blockIdx.x * blockDim.x + threadIdx.x; idx < total;
       idx += (long long)gridDim.x * blockDim.x)
    out[idx] /= fmaxf(colsum[idx & 63], kEps);
}

__global__ __launch_bounds__(256) void score_kernel_norm(
    const float* __restrict__ outLast, const int* __restrict__ t_index,
    const int* __restrict__ hr_inverse, const float* __restrict__ lin_w,
    const float* __restrict__ lin_b, float* __restrict__ out, int n) {
  const int i = blockIdx.x * blockDim.x + threadIdx.x;
  if (i < n) {
    out[i] = outLast[(long long)t_index[i] * kB + hr_inverse[i]] * lin_w[0] + lin_b[0];
  }
}

}  // namespace

extern "C" void kernel_launch(void* const* d_in, const int* in_sizes, int n_in,
                              void* d_out, int out_size, void* d_ws, size_t ws_size,
                              hipStream_t stream) {
  const float* query_emb = (const float*)d_in[0];
  const float* w_ih = (const float*)d_in[1];
  const float* w_hh = (const float*)d_in[2];
  const float* b_ih = (const float*)d_in[3];
  const float* b_hh = (const float*)d_in[4];
  const float* wl_w = (const float*)d_in[5];
  const float* wl_b = (const float*)d_in[6];
  const float* lin_w = (const float*)d_in[7];
  const float* lin_b = (const float*)d_in[8];
  const int* edge_index = (const int*)d_in[9];
  const int* edge_type = (const int*)d_in[10];
  const int* h_set = (const int*)d_in[11];
  const int* r_set = (const int*)d_in[12];
  const int* t_index = (const int*)d_in[13];
  const int* hr_inverse = (const int*)d_in[14];
  float* out = (float*)d_out;

  const int* nin = edge_index;
  const int* nout = edge_index + kNE;

  // ---- workspace layout (identical footprint to round 2) ----
  float* ws = (float*)d_ws;
  float* hidden = ws;                                   // 6*64*128
  float* attnAll = hidden + kNStep * kB * kHid;         // 6*6*64
  float* weightAll = attnAll + kNStep * kNStep * kB;    // 6*24*64
  float* colsumAll = weightAll + kNStep * kNRel2 * kB;  // 6*64
  float* inpF32 = colsumAll + kNStep * kB;              // N1*64 (fallback path)
  __half* inpH = (__half*)inpF32;                       // fp16 view, main path
  float* outs = inpF32 + (long long)kN1 * kB;           // 6*N1*64
  float* tail = outs + (long long)kNStep * kN1 * kB;
  int* counts = (int*)tail;                             // N1
  int* offsets = counts + kN1;                          // N1+1
  int* cursor = offsets + kN1 + 1;                      // N1
  unsigned* packed = (unsigned*)(cursor + kN1);         // NE
  const size_t needed = (size_t)((char*)(packed + kNE) - (char*)d_ws);

  lstm_kernel<<<kB, 256, 0, stream>>>(query_emb, w_ih, w_hh, b_ih, b_hh, r_set, hidden);
  attn_weight_kernel<<<kB, 128, 0, stream>>>(hidden, wl_w, wl_b, attnAll, weightAll);

  if (ws_size >= needed) {
    // ---- sorted-gather path (no float atomics, fp16 L2-resident inp) ----
    zero_kernel<<<(kN1 + 255) / 256, 256, 0, stream>>>(counts, colsumAll);
    hist_kernel<<<1024, 256, 0, stream>>>(nout, counts);
    scan_kernel<<<1, 1024, 0, stream>>>(counts, offsets, cursor);
    permute_kernel<<<1024, 256, 0, stream>>>(nin, nout, edge_type, cursor, packed);

    for (int i = 0; i < kNStep; ++i) {
      float* out_i = outs + (long long)i * kN1 * kB;
      inp_kernel<<<2048, 256, 0, stream>>>(attnAll, colsumAll, h_set, outs, inpH, i);
      gather_edges_kernel<<<(kN1 + 3) / 4, 256, 0, stream>>>(
          inpH, weightAll + i * kNRel2 * kB, packed, offsets, out_i,
          colsumAll + i * kB);
    }
    score_kernel<<<(out_size + 255) / 256, 256, 0, stream>>>(
        outs + 5LL * kN1 * kB, colsumAll + 5 * kB, t_index, hr_inverse, lin_w, lin_b,
        out, out_size);
  } else {
    // ---- fallback: atomic path ----
    float* colsum = colsumAll;
    for (int i = 0; i < kNStep; ++i) {
      float* out_i = outs + (long long)i * kN1 * kB;
      inp_zero_kernel<<<2048, 256, 0, stream>>>(attnAll, h_set, outs, inpF32, out_i,
                                                colsum, i);
      scatter_kernel<<<4096, 256, 0, stream>>>(inpF32, weightAll + i * kNRel2 * kB,
                                               nin, nout, edge_type, out_i, colsum);
      normalize_kernel<<<2048, 256, 0, stream>>>(out_i, colsum);
    }
    score_kernel_norm<<<(out_size + 255) / 256, 256, 0, stream>>>(
        outs + 5LL * kN1 * kB, t_index, hr_inverse, lin_w, lin_b, out, out_size);
  }
}

// Round 4
// 1080.514 us; speedup vs baseline: 3.4814x; 1.0185x over previous
//
#include <hip/hip_runtime.h>
#include <hip/hip_fp16.h>
#include <math.h>

namespace {

constexpr int kN1 = 20001;        // NUM_NODES + 1 (real rows)
constexpr int kNE = 1000000;      // NUM_EDGES
constexpr int kNStep = 6;
constexpr int kHid = 128;
constexpr int kB = 64;            // B_SET
constexpr int kNRel2 = 24;        // 2*NUM_REL
constexpr float kEps = 1e-10f;
constexpr unsigned kSent = (unsigned)kN1;  // sentinel: src = zero row, etype = 0

__device__ __forceinline__ float sig(float x) { return 1.0f / (1.0f + expf(-x)); }

__device__ __forceinline__ float2 cvt2(unsigned u) {
  __half2 h = *reinterpret_cast<__half2*>(&u);
  return __half22float2(h);
}

// ---------------- tiny front-end ----------------

__global__ __launch_bounds__(256) void lstm_kernel(
    const float* __restrict__ query_emb, const float* __restrict__ w_ih,
    const float* __restrict__ w_hh, const float* __restrict__ b_ih,
    const float* __restrict__ b_hh, const int* __restrict__ r_set,
    float* __restrict__ hidden /* (6,64,128) */) {
  const int b = blockIdx.x;
  const int tid = threadIdx.x;
  __shared__ float xs[kHid], hs[kHid], cs[kHid], gates[4 * kHid];
  if (tid < kHid) { hs[tid] = 0.f; cs[tid] = 0.f; }
  __syncthreads();
  for (int s = 0; s < kNStep; ++s) {
    const int q = (s < kNStep - 1) ? r_set[b] : 12;
    if (tid < kHid) xs[tid] = query_emb[q * kHid + tid];
    __syncthreads();
    for (int j = tid; j < 4 * kHid; j += blockDim.x) {
      const float* wi = &w_ih[j * kHid];
      const float* wh = &w_hh[j * kHid];
      float a = b_ih[j] + b_hh[j];
#pragma unroll 4
      for (int k = 0; k < kHid; ++k) a += xs[k] * wi[k] + hs[k] * wh[k];
      gates[j] = a;
    }
    __syncthreads();
    if (tid < kHid) {
      const float ig = sig(gates[tid]);
      const float fg = sig(gates[kHid + tid]);
      const float gg = tanhf(gates[2 * kHid + tid]);
      const float og = sig(gates[3 * kHid + tid]);
      const float cn = fg * cs[tid] + ig * gg;
      const float hn = og * tanhf(cn);
      cs[tid] = cn;
      hs[tid] = hn;
      hidden[(s * kB + b) * kHid + tid] = hn;
    }
    __syncthreads();
  }
}

__global__ __launch_bounds__(128) void attn_weight_kernel(
    const float* __restrict__ hidden, const float* __restrict__ wl_w,
    const float* __restrict__ wl_b, float* __restrict__ attnAll /* (6,6,64) */,
    float* __restrict__ weightAll /* (6,24,64) */) {
  const int b = blockIdx.x;
  const int tid = threadIdx.x;
  __shared__ float hsm[kNStep][kHid];
  __shared__ float G[kNStep][kNStep];
  __shared__ float logits[kNStep][kNRel2];
  for (int s = 0; s < kNStep; ++s) hsm[s][tid] = hidden[(s * kB + b) * kHid + tid];
  __syncthreads();
  if (tid < 36) {
    const int i = tid / 6, t = tid % 6;
    if (t <= i) {
      float acc = 0.f;
      for (int k = 0; k < kHid; ++k) acc += hsm[i][k] * hsm[t][k];
      G[i][t] = acc;
    }
  }
  for (int p = tid; p < kNStep * kNRel2; p += 128) {
    const int i = p / kNRel2, r = p % kNRel2;
    float acc = wl_b[r];
    for (int k = 0; k < kHid; ++k) acc += hsm[i][k] * wl_w[r * kHid + k];
    logits[i][r] = acc;
  }
  __syncthreads();
  if (tid < kNStep) {
    const int i = tid;
    float m = G[i][0];
    for (int t = 1; t <= i; ++t) m = fmaxf(m, G[i][t]);
    float ssum = 0.f;
    float ev[kNStep];
    for (int t = 0; t <= i; ++t) { ev[t] = expf(G[i][t] - m); ssum += ev[t]; }
    for (int t = 0; t <= i; ++t) attnAll[(i * kNStep + t) * kB + b] = ev[t] / ssum;
    float mw = logits[i][0];
    for (int r = 1; r < kNRel2; ++r) mw = fmaxf(mw, logits[i][r]);
    float sw = 0.f;
    float ew[kNRel2];
    for (int r = 0; r < kNRel2; ++r) { ew[r] = expf(logits[i][r] - mw); sw += ew[r]; }
    for (int r = 0; r < kNRel2; ++r) weightAll[(i * kNRel2 + r) * kB + b] = ew[r] / sw;
  }
}

// ---------------- edge preprocessing (once per launch) ----------------

__global__ __launch_bounds__(256) void zero_kernel(int* __restrict__ counts,
                                                   float* __restrict__ colsumAll) {
  const int i = blockIdx.x * blockDim.x + threadIdx.x;
  if (i < kN1) counts[i] = 0;
  if (i < kNStep * kB) colsumAll[i] = 0.f;
}

__global__ __launch_bounds__(256) void hist_kernel(const int* __restrict__ nout,
                                                   int* __restrict__ counts) {
  for (int e = blockIdx.x * blockDim.x + threadIdx.x; e < kNE;
       e += gridDim.x * blockDim.x)
    atomicAdd(&counts[nout[e]], 1);
}

__global__ __launch_bounds__(1024) void scan_kernel(const int* __restrict__ counts,
                                                    int* __restrict__ offsets,
                                                    int* __restrict__ cursor) {
  __shared__ int part[1024];
  const int tid = threadIdx.x;
  const int chunk = (kN1 + 1023) / 1024;  // 20
  const int beg = tid * chunk;
  const int end = min(beg + chunk, kN1);
  int s = 0;
  for (int i = beg; i < end; ++i) s += counts[i];
  part[tid] = s;
  __syncthreads();
  for (int off = 1; off < 1024; off <<= 1) {
    const int v = (tid >= off) ? part[tid - off] : 0;
    __syncthreads();
    part[tid] += v;
    __syncthreads();
  }
  int run = part[tid] - s;  // exclusive prefix of this chunk
  for (int i = beg; i < end; ++i) {
    offsets[i] = run;
    cursor[i] = run;
    run += counts[i];
  }
  if (tid == 1023) offsets[kN1] = part[1023];
}

__global__ __launch_bounds__(256) void permute_kernel(
    const int* __restrict__ nin, const int* __restrict__ nout,
    const int* __restrict__ etype, int* __restrict__ cursor,
    unsigned* __restrict__ packed) {
  for (int e = blockIdx.x * blockDim.x + threadIdx.x; e < kNE;
       e += gridDim.x * blockDim.x) {
    const int d = nout[e];
    const int pos = atomicAdd(&cursor[d], 1);
    packed[pos] = (unsigned)nin[e] | ((unsigned)etype[e] << 15);
  }
}

// ---------------- per-step kernels ----------------

// One thread per (node, 4-col group). inp has kN1+1 rows; row kN1 is the
// zero sentinel row used by the gather's tail lanes.
__global__ __launch_bounds__(256) void inp_kernel(
    const float* __restrict__ attnAll, const float* __restrict__ colsumAll,
    const int* __restrict__ h_set, const float* __restrict__ outs,
    __half* __restrict__ inp, int step) {
  __shared__ float coef[kNStep][kB];
  __shared__ int hsm[kB];
  const int tid = threadIdx.x;
  for (int j = tid; j < kNStep * kB; j += 256) {   // FIX: full 384-entry fill
    const int t = j >> 6, b = j & 63;
    float c = 0.f;
    if (t == 0)
      c = attnAll[(step * kNStep) * kB + b];
    else if (t <= step)
      c = attnAll[(step * kNStep + t) * kB + b] /
          fmaxf(colsumAll[(t - 1) * kB + b], kEps);
    coef[t][b] = c;
  }
  if (tid < kB) hsm[tid] = h_set[tid];
  __syncthreads();
  const int total = (kN1 + 1) * 16;
  for (int idx = blockIdx.x * blockDim.x + tid; idx < total;
       idx += gridDim.x * blockDim.x) {
    const int n = idx >> 4;
    const int cg = idx & 15;  // columns cg*4 .. cg*4+3
    float ax = 0.f, ay = 0.f, az = 0.f, aw = 0.f;
    if (n < kN1) {
      for (int t = 1; t <= step; ++t) {
        const float4 ct = *reinterpret_cast<const float4*>(&coef[t][cg * 4]);
        const float4 o = *reinterpret_cast<const float4*>(
            &outs[((long long)(t - 1) * kN1 + n) * kB + cg * 4]);
        ax += ct.x * o.x; ay += ct.y * o.y; az += ct.z * o.z; aw += ct.w * o.w;
      }
      const int c0 = cg * 4;
      if (hsm[c0 + 0] == n) ax += coef[0][c0 + 0];
      if (hsm[c0 + 1] == n) ay += coef[0][c0 + 1];
      if (hsm[c0 + 2] == n) az += coef[0][c0 + 2];
      if (hsm[c0 + 3] == n) aw += coef[0][c0 + 3];
    }
    __half2 h0 = __floats2half2_rn(ax, ay);
    __half2 h1 = __floats2half2_rn(az, aw);
    uint2 u;
    u.x = *reinterpret_cast<unsigned*>(&h0);
    u.y = *reinterpret_cast<unsigned*>(&h1);
    *reinterpret_cast<uint2*>(inp + (long long)idx * 4) = u;
  }
}

// One wave per destination node; 8 lane-groups process 8 edges/iteration.
// Lane = (group g = lane>>3, column block cb = lane&7). Each lane gathers
// 8 fp16 columns (16 B) of its group's edge row -> 2 vmem instr per 8 edges.
__global__ __launch_bounds__(256) void gather_edges_kernel(
    const __half* __restrict__ inp /* (kN1+1, 64) */,
    const float* __restrict__ weight /* (24,64) */,
    const unsigned* __restrict__ packed, const int* __restrict__ offsets,
    float* __restrict__ out, float* __restrict__ colsum) {
  __shared__ __align__(16) __half wsm[kNRel2 * kB];
  __shared__ float red[4][kB];
  const int tid = threadIdx.x;
  const int lane = tid & 63;
  const int wid = tid >> 6;
  const int g = lane >> 3;   // edge slot within iteration
  const int cb = lane & 7;   // 8-column block
  for (int j = tid; j < kNRel2 * kB; j += 256) wsm[j] = __float2half(weight[j]);
  __syncthreads();
  const int node = blockIdx.x * 4 + wid;
  float acc[8] = {0.f, 0.f, 0.f, 0.f, 0.f, 0.f, 0.f, 0.f};
  if (node < kN1) {
    const int beg = offsets[node];
    const int end = offsets[node + 1];
    for (int e = beg; e < end; e += 8) {
      const int idx = e + g;
      const unsigned pr = packed[min(idx, end - 1)];
      const unsigned p = (idx < end) ? pr : kSent;
      const int src = (int)(p & 0x7fffu);
      const int et = (int)(p >> 15);
      const uint4 v4 =
          *reinterpret_cast<const uint4*>(inp + (long long)src * kB + cb * 8);
      const uint4 w4 = *reinterpret_cast<const uint4*>(wsm + et * kB + cb * 8);
      const float2 v0 = cvt2(v4.x), v1 = cvt2(v4.y), v2 = cvt2(v4.z), v3 = cvt2(v4.w);
      const float2 w0 = cvt2(w4.x), w1 = cvt2(w4.y), w2 = cvt2(w4.z), w3 = cvt2(w4.w);
      acc[0] += v0.x * w0.x; acc[1] += v0.y * w0.y;
      acc[2] += v1.x * w1.x; acc[3] += v1.y * w1.y;
      acc[4] += v2.x * w2.x; acc[5] += v2.y * w2.y;
      acc[6] += v3.x * w3.x; acc[7] += v3.y * w3.y;
    }
  }
  // Reduce across the 8 groups (lanes L, L^8, L^16, L^32 hold same columns).
#pragma unroll
  for (int j = 0; j < 8; ++j) {
    acc[j] += __shfl_xor(acc[j], 8);
    acc[j] += __shfl_xor(acc[j], 16);
    acc[j] += __shfl_xor(acc[j], 32);
  }
  if (g == 0) {
    if (node < kN1) {
      float4 o0 = make_float4(acc[0], acc[1], acc[2], acc[3]);
      float4 o1 = make_float4(acc[4], acc[5], acc[6], acc[7]);
      *reinterpret_cast<float4*>(out + (long long)node * kB + cb * 8) = o0;
      *reinterpret_cast<float4*>(out + (long long)node * kB + cb * 8 + 4) = o1;
    }
#pragma unroll
    for (int j = 0; j < 8; ++j) red[wid][cb * 8 + j] = (node < kN1) ? acc[j] : 0.f;
  }
  __syncthreads();
  if (wid == 0) {
    const float r = red[0][lane] + red[1][lane] + red[2][lane] + red[3][lane];
    unsafeAtomicAdd(&colsum[lane], r);
  }
}

__global__ __launch_bounds__(256) void score_kernel(
    const float* __restrict__ outLast, const float* __restrict__ colsumLast,
    const int* __restrict__ t_index, const int* __restrict__ hr_inverse,
    const float* __restrict__ lin_w, const float* __restrict__ lin_b,
    float* __restrict__ out, int n) {
  const int i = blockIdx.x * blockDim.x + threadIdx.x;
  if (i < n) {
    const int node = t_index[i];
    const int b = hr_inverse[i];
    const float v = outLast[(long long)node * kB + b] / fmaxf(colsumLast[b], kEps);
    out[i] = v * lin_w[0] + lin_b[0];
  }
}

// ---------------- fallback (float-atomic scatter) ----------------

__global__ __launch_bounds__(256) void inp_zero_kernel(
    const float* __restrict__ attnAll, const int* __restrict__ h_set,
    const float* __restrict__ outs, float* __restrict__ inp,
    float* __restrict__ out_next, float* __restrict__ colsum, int step) {
  const long long total = (long long)kN1 * kB;
  for (long long idx = (long long)blockIdx.x * blockDim.x + threadIdx.x; idx < total;
       idx += (long long)gridDim.x * blockDim.x) {
    const int b = (int)(idx & 63);
    const int n = (int)(idx >> 6);
    float acc = (h_set[b] == n) ? attnAll[(step * kNStep) * kB + b] : 0.f;
    for (int t = 1; t <= step; ++t)
      acc += attnAll[(step * kNStep + t) * kB + b] *
             outs[(long long)(t - 1) * kN1 * kB + idx];
    inp[idx] = acc;
    out_next[idx] = 0.f;
  }
  if (blockIdx.x == 0 && threadIdx.x < kB) colsum[threadIdx.x] = 0.f;
}

__global__ __launch_bounds__(256) void scatter_kernel(
    const float* __restrict__ inp, const float* __restrict__ weight,
    const int* __restrict__ nin, const int* __restrict__ nout,
    const int* __restrict__ etype, float* __restrict__ out,
    float* __restrict__ colsum) {
  const int lane = threadIdx.x & 63;
  const int wave = blockIdx.x * (blockDim.x >> 6) + (threadIdx.x >> 6);
  const int nwave = gridDim.x * (blockDim.x >> 6);
  __shared__ float wsm[kNRel2 * kB];
  for (int j = threadIdx.x; j < kNRel2 * kB; j += blockDim.x) wsm[j] = weight[j];
  __syncthreads();
  float csum = 0.f;
  for (int e = wave; e < kNE; e += nwave) {
    const float v = inp[(long long)nin[e] * kB + lane] * wsm[etype[e] * kB + lane];
    unsafeAtomicAdd(&out[(long long)nout[e] * kB + lane], v);
    csum += v;
  }
  unsafeAtomicAdd(&colsum[lane], csum);
}

__global__ __launch_bounds__(256) void normalize_kernel(
    float* __restrict__ out, const float* __restrict__ colsum) {
  const long long total = (long long)kN1 * kB;
  for (long long idx = (long long)blockIdx.x * blockDim.x + threadIdx.x; idx < total;
       idx += (long long)gridDim.x * blockDim.x)
    out[idx] /= fmaxf(colsum[idx & 63], kEps);
}

__global__ __launch_bounds__(256) void score_kernel_norm(
    const float* __restrict__ outLast, const int* __restrict__ t_index,
    const int* __restrict__ hr_inverse, const float* __restrict__ lin_w,
    const float* __restrict__ lin_b, float* __restrict__ out, int n) {
  const int i = blockIdx.x * blockDim.x + threadIdx.x;
  if (i < n) {
    out[i] = outLast[(long long)t_index[i] * kB + hr_inverse[i]] * lin_w[0] + lin_b[0];
  }
}

}  // namespace

extern "C" void kernel_launch(void* const* d_in, const int* in_sizes, int n_in,
                              void* d_out, int out_size, void* d_ws, size_t ws_size,
                              hipStream_t stream) {
  const float* query_emb = (const float*)d_in[0];
  const float* w_ih = (const float*)d_in[1];
  const float* w_hh = (const float*)d_in[2];
  const float* b_ih = (const float*)d_in[3];
  const float* b_hh = (const float*)d_in[4];
  const float* wl_w = (const float*)d_in[5];
  const float* wl_b = (const float*)d_in[6];
  const float* lin_w = (const float*)d_in[7];
  const float* lin_b = (const float*)d_in[8];
  const int* edge_index = (const int*)d_in[9];
  const int* edge_type = (const int*)d_in[10];
  const int* h_set = (const int*)d_in[11];
  const int* r_set = (const int*)d_in[12];
  const int* t_index = (const int*)d_in[13];
  const int* hr_inverse = (const int*)d_in[14];
  float* out = (float*)d_out;

  const int* nin = edge_index;
  const int* nout = edge_index + kNE;

  // ---- workspace layout (same footprint as round 3) ----
  float* ws = (float*)d_ws;
  float* hidden = ws;                                   // 6*64*128
  float* attnAll = hidden + kNStep * kB * kHid;         // 6*6*64
  float* weightAll = attnAll + kNStep * kNStep * kB;    // 6*24*64
  float* colsumAll = weightAll + kNStep * kNRel2 * kB;  // 6*64
  float* inpF32 = colsumAll + kNStep * kB;              // kN1*64 f32 slot
  __half* inpH = (__half*)inpF32;                       // (kN1+1)*64 fp16 view (fits)
  float* outs = inpF32 + (long long)kN1 * kB;           // 6*kN1*64
  float* tail = outs + (long long)kNStep * kN1 * kB;
  int* counts = (int*)tail;                             // kN1
  int* offsets = counts + kN1;                          // kN1+1
  int* cursor = offsets + kN1 + 1;                      // kN1
  unsigned* packed = (unsigned*)(cursor + kN1);         // kNE
  const size_t needed = (size_t)((char*)(packed + kNE) - (char*)d_ws);

  lstm_kernel<<<kB, 256, 0, stream>>>(query_emb, w_ih, w_hh, b_ih, b_hh, r_set, hidden);
  attn_weight_kernel<<<kB, 128, 0, stream>>>(hidden, wl_w, wl_b, attnAll, weightAll);

  if (ws_size >= needed) {
    zero_kernel<<<(kN1 + 255) / 256, 256, 0, stream>>>(counts, colsumAll);
    hist_kernel<<<1024, 256, 0, stream>>>(nout, counts);
    scan_kernel<<<1, 1024, 0, stream>>>(counts, offsets, cursor);
    permute_kernel<<<1024, 256, 0, stream>>>(nin, nout, edge_type, cursor, packed);

    const int inp_threads = (kN1 + 1) * 16;
    for (int i = 0; i < kNStep; ++i) {
      float* out_i = outs + (long long)i * kN1 * kB;
      inp_kernel<<<(inp_threads + 255) / 256, 256, 0, stream>>>(
          attnAll, colsumAll, h_set, outs, inpH, i);
      gather_edges_kernel<<<(kN1 + 3) / 4, 256, 0, stream>>>(
          inpH, weightAll + i * kNRel2 * kB, packed, offsets, out_i,
          colsumAll + i * kB);
    }
    score_kernel<<<(out_size + 255) / 256, 256, 0, stream>>>(
        outs + 5LL * kN1 * kB, colsumAll + 5 * kB, t_index, hr_inverse, lin_w, lin_b,
        out, out_size);
  } else {
    float* colsum = colsumAll;
    for (int i = 0; i < kNStep; ++i) {
      float* out_i = outs + (long long)i * kN1 * kB;
      inp_zero_kernel<<<2048, 256, 0, stream>>>(attnAll, h_set, outs, inpF32, out_i,
                                                colsum, i);
      scatter_kernel<<<4096, 256, 0, stream>>>(inpF32, weightAll + i * kNRel2 * kB,
                                               nin, nout, edge_type, out_i, colsum);
      normalize_kernel<<<2048, 256, 0, stream>>>(out_i, colsum);
    }
    score_kernel_norm<<<(out_size + 255) / 256, 256, 0, stream>>>(
        outs + 5LL * kN1 * kB, t_index, hr_inverse, lin_w, lin_b, out, out_size);
  }
}

// Round 5
// 715.881 us; speedup vs baseline: 5.2547x; 1.5093x over previous
//
#include <hip/hip_runtime.h>
#include <hip/hip_fp16.h>
#include <math.h>

namespace {

constexpr int kN1 = 20001;        // NUM_NODES + 1 (output rows)
constexpr int kNE = 1000000;      // NUM_EDGES
constexpr int kNStep = 6;
constexpr int kHid = 128;
constexpr int kB = 64;            // B_SET
constexpr int kNRel2 = 24;        // 2*NUM_REL
constexpr float kEps = 1e-10f;
constexpr unsigned kSent = (unsigned)kN1;     // sentinel src = zero row, etype 0
constexpr int kPMax = kNE + 8 * kN1;          // padded edge array bound
constexpr int kGatherBlocks = 2048;           // 8192 waves
constexpr int kNWaves = kGatherBlocks * 4;

__device__ __forceinline__ float sig(float x) { return 1.0f / (1.0f + expf(-x)); }

__device__ __forceinline__ float2 cvt2(unsigned u) {
  __half2 h = *reinterpret_cast<__half2*>(&u);
  return __half22float2(h);
}

// ---------------- tiny front-end ----------------

__global__ __launch_bounds__(256) void lstm_kernel(
    const float* __restrict__ query_emb, const float* __restrict__ w_ih,
    const float* __restrict__ w_hh, const float* __restrict__ b_ih,
    const float* __restrict__ b_hh, const int* __restrict__ r_set,
    float* __restrict__ hidden /* (6,64,128) */) {
  const int b = blockIdx.x;
  const int tid = threadIdx.x;
  __shared__ float xs[kHid], hs[kHid], cs[kHid], gates[4 * kHid];
  if (tid < kHid) { hs[tid] = 0.f; cs[tid] = 0.f; }
  __syncthreads();
  for (int s = 0; s < kNStep; ++s) {
    const int q = (s < kNStep - 1) ? r_set[b] : 12;
    if (tid < kHid) xs[tid] = query_emb[q * kHid + tid];
    __syncthreads();
    for (int j = tid; j < 4 * kHid; j += blockDim.x) {
      const float* wi = &w_ih[j * kHid];
      const float* wh = &w_hh[j * kHid];
      float a = b_ih[j] + b_hh[j];
#pragma unroll 4
      for (int k = 0; k < kHid; ++k) a += xs[k] * wi[k] + hs[k] * wh[k];
      gates[j] = a;
    }
    __syncthreads();
    if (tid < kHid) {
      const float ig = sig(gates[tid]);
      const float fg = sig(gates[kHid + tid]);
      const float gg = tanhf(gates[2 * kHid + tid]);
      const float og = sig(gates[3 * kHid + tid]);
      const float cn = fg * cs[tid] + ig * gg;
      const float hn = og * tanhf(cn);
      cs[tid] = cn;
      hs[tid] = hn;
      hidden[(s * kB + b) * kHid + tid] = hn;
    }
    __syncthreads();
  }
}

__global__ __launch_bounds__(128) void attn_weight_kernel(
    const float* __restrict__ hidden, const float* __restrict__ wl_w,
    const float* __restrict__ wl_b, float* __restrict__ attnAll /* (6,6,64) */,
    float* __restrict__ weightAll /* (6,24,64) */) {
  const int b = blockIdx.x;
  const int tid = threadIdx.x;
  __shared__ float hsm[kNStep][kHid];
  __shared__ float G[kNStep][kNStep];
  __shared__ float logits[kNStep][kNRel2];
  for (int s = 0; s < kNStep; ++s) hsm[s][tid] = hidden[(s * kB + b) * kHid + tid];
  __syncthreads();
  if (tid < 36) {
    const int i = tid / 6, t = tid % 6;
    if (t <= i) {
      float acc = 0.f;
      for (int k = 0; k < kHid; ++k) acc += hsm[i][k] * hsm[t][k];
      G[i][t] = acc;
    }
  }
  for (int p = tid; p < kNStep * kNRel2; p += 128) {
    const int i = p / kNRel2, r = p % kNRel2;
    float acc = wl_b[r];
    for (int k = 0; k < kHid; ++k) acc += hsm[i][k] * wl_w[r * kHid + k];
    logits[i][r] = acc;
  }
  __syncthreads();
  if (tid < kNStep) {
    const int i = tid;
    float m = G[i][0];
    for (int t = 1; t <= i; ++t) m = fmaxf(m, G[i][t]);
    float ssum = 0.f;
    float ev[kNStep];
    for (int t = 0; t <= i; ++t) { ev[t] = expf(G[i][t] - m); ssum += ev[t]; }
    for (int t = 0; t <= i; ++t) attnAll[(i * kNStep + t) * kB + b] = ev[t] / ssum;
    float mw = logits[i][0];
    for (int r = 1; r < kNRel2; ++r) mw = fmaxf(mw, logits[i][r]);
    float sw = 0.f;
    float ew[kNRel2];
    for (int r = 0; r < kNRel2; ++r) { ew[r] = expf(logits[i][r] - mw); sw += ew[r]; }
    for (int r = 0; r < kNRel2; ++r) weightAll[(i * kNRel2 + r) * kB + b] = ew[r] / sw;
  }
}

// ---------------- edge preprocessing (once per launch) ----------------

__global__ __launch_bounds__(256) void zero_kernel(int* __restrict__ counts,
                                                   float* __restrict__ colsumAll) {
  const int i = blockIdx.x * blockDim.x + threadIdx.x;
  if (i < kN1) counts[i] = 0;
  if (i < kNStep * kB) colsumAll[i] = 0.f;
}

__global__ __launch_bounds__(256) void hist_kernel(const int* __restrict__ nout,
                                                   int* __restrict__ counts) {
  for (int e = blockIdx.x * blockDim.x + threadIdx.x; e < kNE;
       e += gridDim.x * blockDim.x)
    atomicAdd(&counts[nout[e]], 1);
}

// Exclusive scan of PADDED counts ((c+7)&~7). poffsets has kN1+1 entries.
__global__ __launch_bounds__(1024) void scan_kernel(const int* __restrict__ counts,
                                                    int* __restrict__ poffsets,
                                                    int* __restrict__ cursor) {
  __shared__ int part[1024];
  const int tid = threadIdx.x;
  const int chunk = (kN1 + 1023) / 1024;  // 20
  const int beg = tid * chunk;
  const int end = min(beg + chunk, kN1);
  int s = 0;
  for (int i = beg; i < end; ++i) s += (counts[i] + 7) & ~7;
  part[tid] = s;
  __syncthreads();
  for (int off = 1; off < 1024; off <<= 1) {
    const int v = (tid >= off) ? part[tid - off] : 0;
    __syncthreads();
    part[tid] += v;
    __syncthreads();
  }
  int run = part[tid] - s;  // exclusive prefix of this chunk
  for (int i = beg; i < end; ++i) {
    poffsets[i] = run;
    cursor[i] = run;
    run += (counts[i] + 7) & ~7;
  }
  if (tid == 1023) poffsets[kN1] = part[1023];
}

__global__ __launch_bounds__(256) void fill_kernel(unsigned* __restrict__ packed) {
  for (int i = blockIdx.x * blockDim.x + threadIdx.x; i < kPMax;
       i += gridDim.x * blockDim.x)
    packed[i] = kSent;
}

__global__ __launch_bounds__(256) void permute_kernel(
    const int* __restrict__ nin, const int* __restrict__ nout,
    const int* __restrict__ etype, int* __restrict__ cursor,
    unsigned* __restrict__ packed) {
  for (int e = blockIdx.x * blockDim.x + threadIdx.x; e < kNE;
       e += gridDim.x * blockDim.x) {
    const int d = nout[e];
    const int pos = atomicAdd(&cursor[d], 1);
    packed[pos] = (unsigned)nin[e] | ((unsigned)etype[e] << 15);
  }
}

// ---------------- per-step kernels ----------------

// One thread per (node, 4-col group). inp has kN1+1 rows; row kN1 is the
// zero sentinel row used by padding edges.
__global__ __launch_bounds__(256) void inp_kernel(
    const float* __restrict__ attnAll, const float* __restrict__ colsumAll,
    const int* __restrict__ h_set, const float* __restrict__ outs,
    __half* __restrict__ inp, int step) {
  __shared__ float coef[kNStep][kB];
  __shared__ int hsm[kB];
  const int tid = threadIdx.x;
  for (int j = tid; j < kNStep * kB; j += 256) {
    const int t = j >> 6, b = j & 63;
    float c = 0.f;
    if (t == 0)
      c = attnAll[(step * kNStep) * kB + b];
    else if (t <= step)
      c = attnAll[(step * kNStep + t) * kB + b] /
          fmaxf(colsumAll[(t - 1) * kB + b], kEps);
    coef[t][b] = c;
  }
  if (tid < kB) hsm[tid] = h_set[tid];
  __syncthreads();
  const int total = (kN1 + 1) * 16;
  for (int idx = blockIdx.x * blockDim.x + tid; idx < total;
       idx += gridDim.x * blockDim.x) {
    const int n = idx >> 4;
    const int cg = idx & 15;  // columns cg*4 .. cg*4+3
    float ax = 0.f, ay = 0.f, az = 0.f, aw = 0.f;
    if (n < kN1) {
      for (int t = 1; t <= step; ++t) {
        const float4 ct = *reinterpret_cast<const float4*>(&coef[t][cg * 4]);
        const float4 o = *reinterpret_cast<const float4*>(
            &outs[((long long)(t - 1) * kN1 + n) * kB + cg * 4]);
        ax += ct.x * o.x; ay += ct.y * o.y; az += ct.z * o.z; aw += ct.w * o.w;
      }
      const int c0 = cg * 4;
      if (hsm[c0 + 0] == n) ax += coef[0][c0 + 0];
      if (hsm[c0 + 1] == n) ay += coef[0][c0 + 1];
      if (hsm[c0 + 2] == n) az += coef[0][c0 + 2];
      if (hsm[c0 + 3] == n) aw += coef[0][c0 + 3];
    }
    __half2 h0 = __floats2half2_rn(ax, ay);
    __half2 h1 = __floats2half2_rn(az, aw);
    uint2 u;
    u.x = *reinterpret_cast<unsigned*>(&h0);
    u.y = *reinterpret_cast<unsigned*>(&h1);
    *reinterpret_cast<uint2*>(inp + (long long)idx * 4) = u;
  }
}

// Persistent-wave segmented SpMV over the padded, dst-sorted edge array.
// Wave owns all nodes whose padded bin STARTS in its group window
// [gbeg*8, gend*8). 8 lane-groups (g=lane>>3) each handle one edge of the
// current 8-edge group; lane covers 8 fp16 columns (cb=lane&7). Node flush =
// 3 shfl_xor + plain store (exclusive ownership, no atomics on out).
__global__ __launch_bounds__(256) void gather_seg_kernel(
    const __half* __restrict__ inp /* (kN1+1, 64) */,
    const float* __restrict__ weight /* (24,64) */,
    const unsigned* __restrict__ packed, const int* __restrict__ poffsets,
    float* __restrict__ out, float* __restrict__ colsum) {
  __shared__ __align__(16) __half wsm[kNRel2 * kB];
  __shared__ float red[4][kB];
  const int tid = threadIdx.x;
  const int lane = tid & 63;
  const int wid = tid >> 6;
  const int g = lane >> 3;   // edge slot within group
  const int cb = lane & 7;   // 8-column block
  for (int j = tid; j < kNRel2 * kB; j += 256) wsm[j] = __float2half(weight[j]);
  __syncthreads();

  float csum[8] = {0.f, 0.f, 0.f, 0.f, 0.f, 0.f, 0.f, 0.f};
  const int wave = blockIdx.x * 4 + wid;
  const int P = poffsets[kN1];
  const int nG = P >> 3;
  const int chunkG = (nG + kNWaves - 1) / kNWaves;
  const int gbeg = wave * chunkG;
  if (gbeg < nG) {
    const int gend = min(gbeg + chunkG, nG);
    // lower_bound: smallest n with poffsets[n] >= x
    auto lb = [&](int x) {
      int lo = 0, hi = kN1;
      while (lo < hi) {
        const int mid = (lo + hi) >> 1;
        if (poffsets[mid] < x) lo = mid + 1; else hi = mid;
      }
      return lo;
    };
    const int nbeg = lb(gbeg * 8);
    const int nend = (gend >= nG) ? kN1 : lb(gend * 8);
    if (nbeg < nend) {
      float acc[8] = {0.f, 0.f, 0.f, 0.f, 0.f, 0.f, 0.f, 0.f};
      int n = nbeg;
      int nextB = poffsets[n + 1];
      const int ebeg = poffsets[nbeg];
      const int eend = poffsets[nend];
      for (int ebase = ebeg; ebase < eend; ebase += 8) {
        while (ebase >= nextB) {  // flush finished node(s) (wave-uniform)
#pragma unroll
          for (int j = 0; j < 8; ++j) {
            acc[j] += __shfl_xor(acc[j], 8);
            acc[j] += __shfl_xor(acc[j], 16);
            acc[j] += __shfl_xor(acc[j], 32);
          }
          if (g == 0) {
            *reinterpret_cast<float4*>(out + (long long)n * kB + cb * 8) =
                make_float4(acc[0], acc[1], acc[2], acc[3]);
            *reinterpret_cast<float4*>(out + (long long)n * kB + cb * 8 + 4) =
                make_float4(acc[4], acc[5], acc[6], acc[7]);
#pragma unroll
            for (int j = 0; j < 8; ++j) csum[j] += acc[j];
          }
#pragma unroll
          for (int j = 0; j < 8; ++j) acc[j] = 0.f;
          ++n;
          nextB = poffsets[n + 1];
        }
        const unsigned p = packed[ebase + g];
        const int src = (int)(p & 0x7fffu);
        const int et = (int)(p >> 15);
        const uint4 v4 =
            *reinterpret_cast<const uint4*>(inp + (long long)src * kB + cb * 8);
        const uint4 w4 = *reinterpret_cast<const uint4*>(wsm + et * kB + cb * 8);
        const float2 v0 = cvt2(v4.x), v1 = cvt2(v4.y), v2 = cvt2(v4.z), v3 = cvt2(v4.w);
        const float2 w0 = cvt2(w4.x), w1 = cvt2(w4.y), w2 = cvt2(w4.z), w3 = cvt2(w4.w);
        acc[0] += v0.x * w0.x; acc[1] += v0.y * w0.y;
        acc[2] += v1.x * w1.x; acc[3] += v1.y * w1.y;
        acc[4] += v2.x * w2.x; acc[5] += v2.y * w2.y;
        acc[6] += v3.x * w3.x; acc[7] += v3.y * w3.y;
      }
      // flush remaining nodes (last accumulated + trailing empties)
      while (n < nend) {
#pragma unroll
        for (int j = 0; j < 8; ++j) {
          acc[j] += __shfl_xor(acc[j], 8);
          acc[j] += __shfl_xor(acc[j], 16);
          acc[j] += __shfl_xor(acc[j], 32);
        }
        if (g == 0) {
          *reinterpret_cast<float4*>(out + (long long)n * kB + cb * 8) =
              make_float4(acc[0], acc[1], acc[2], acc[3]);
          *reinterpret_cast<float4*>(out + (long long)n * kB + cb * 8 + 4) =
              make_float4(acc[4], acc[5], acc[6], acc[7]);
#pragma unroll
          for (int j = 0; j < 8; ++j) csum[j] += acc[j];
        }
#pragma unroll
        for (int j = 0; j < 8; ++j) acc[j] = 0.f;
        ++n;
      }
    }
  }
  // block-level colsum reduce -> one atomic round per block
  if (g == 0) {
#pragma unroll
    for (int j = 0; j < 8; ++j) red[wid][cb * 8 + j] = csum[j];
  }
  __syncthreads();
  if (wid == 0) {
    const float r = red[0][lane] + red[1][lane] + red[2][lane] + red[3][lane];
    unsafeAtomicAdd(&colsum[lane], r);
  }
}

__global__ __launch_bounds__(256) void score_kernel(
    const float* __restrict__ outLast, const float* __restrict__ colsumLast,
    const int* __restrict__ t_index, const int* __restrict__ hr_inverse,
    const float* __restrict__ lin_w, const float* __restrict__ lin_b,
    float* __restrict__ out, int n) {
  const int i = blockIdx.x * blockDim.x + threadIdx.x;
  if (i < n) {
    const int node = t_index[i];
    const int b = hr_inverse[i];
    const float v = outLast[(long long)node * kB + b] / fmaxf(colsumLast[b], kEps);
    out[i] = v * lin_w[0] + lin_b[0];
  }
}

// ---------------- fallback (float-atomic scatter) ----------------

__global__ __launch_bounds__(256) void inp_zero_kernel(
    const float* __restrict__ attnAll, const int* __restrict__ h_set,
    const float* __restrict__ outs, float* __restrict__ inp,
    float* __restrict__ out_next, float* __restrict__ colsum, int step) {
  const long long total = (long long)kN1 * kB;
  for (long long idx = (long long)blockIdx.x * blockDim.x + threadIdx.x; idx < total;
       idx += (long long)gridDim.x * blockDim.x) {
    const int b = (int)(idx & 63);
    const int n = (int)(idx >> 6);
    float acc = (h_set[b] == n) ? attnAll[(step * kNStep) * kB + b] : 0.f;
    for (int t = 1; t <= step; ++t)
      acc += attnAll[(step * kNStep + t) * kB + b] *
             outs[(long long)(t - 1) * kN1 * kB + idx];
    inp[idx] = acc;
    out_next[idx] = 0.f;
  }
  if (blockIdx.x == 0 && threadIdx.x < kB) colsum[threadIdx.x] = 0.f;
}

__global__ __launch_bounds__(256) void scatter_kernel(
    const float* __restrict__ inp, const float* __restrict__ weight,
    const int* __restrict__ nin, const int* __restrict__ nout,
    const int* __restrict__ etype, float* __restrict__ out,
    float* __restrict__ colsum) {
  const int lane = threadIdx.x & 63;
  const int wave = blockIdx.x * (blockDim.x >> 6) + (threadIdx.x >> 6);
  const int nwave = gridDim.x * (blockDim.x >> 6);
  __shared__ float wsm[kNRel2 * kB];
  for (int j = threadIdx.x; j < kNRel2 * kB; j += blockDim.x) wsm[j] = weight[j];
  __syncthreads();
  float csum = 0.f;
  for (int e = wave; e < kNE; e += nwave) {
    const float v = inp[(long long)nin[e] * kB + lane] * wsm[etype[e] * kB + lane];
    unsafeAtomicAdd(&out[(long long)nout[e] * kB + lane], v);
    csum += v;
  }
  unsafeAtomicAdd(&colsum[lane], csum);
}

__global__ __launch_bounds__(256) void normalize_kernel(
    float* __restrict__ out, const float* __restrict__ colsum) {
  const long long total = (long long)kN1 * kB;
  for (long long idx = (long long)blockIdx.x * blockDim.x + threadIdx.x; idx < total;
       idx += (long long)gridDim.x * blockDim.x)
    out[idx] /= fmaxf(colsum[idx & 63], kEps);
}

__global__ __launch_bounds__(256) void score_kernel_norm(
    const float* __restrict__ outLast, const int* __restrict__ t_index,
    const int* __restrict__ hr_inverse, const float* __restrict__ lin_w,
    const float* __restrict__ lin_b, float* __restrict__ out, int n) {
  const int i = blockIdx.x * blockDim.x + threadIdx.x;
  if (i < n) {
    out[i] = outLast[(long long)t_index[i] * kB + hr_inverse[i]] * lin_w[0] + lin_b[0];
  }
}

}  // namespace

extern "C" void kernel_launch(void* const* d_in, const int* in_sizes, int n_in,
                              void* d_out, int out_size, void* d_ws, size_t ws_size,
                              hipStream_t stream) {
  const float* query_emb = (const float*)d_in[0];
  const float* w_ih = (const float*)d_in[1];
  const float* w_hh = (const float*)d_in[2];
  const float* b_ih = (const float*)d_in[3];
  const float* b_hh = (const float*)d_in[4];
  const float* wl_w = (const float*)d_in[5];
  const float* wl_b = (const float*)d_in[6];
  const float* lin_w = (const float*)d_in[7];
  const float* lin_b = (const float*)d_in[8];
  const int* edge_index = (const int*)d_in[9];
  const int* edge_type = (const int*)d_in[10];
  const int* h_set = (const int*)d_in[11];
  const int* r_set = (const int*)d_in[12];
  const int* t_index = (const int*)d_in[13];
  const int* hr_inverse = (const int*)d_in[14];
  float* out = (float*)d_out;

  const int* nin = edge_index;
  const int* nout = edge_index + kNE;

  // ---- workspace layout ----
  float* ws = (float*)d_ws;
  float* hidden = ws;                                   // 6*64*128
  float* attnAll = hidden + kNStep * kB * kHid;         // 6*6*64
  float* weightAll = attnAll + kNStep * kNStep * kB;    // 6*24*64
  float* colsumAll = weightAll + kNStep * kNRel2 * kB;  // 6*64
  float* inpF32 = colsumAll + kNStep * kB;              // kN1*64 f32 slot
  __half* inpH = (__half*)inpF32;                       // (kN1+1)*64 fp16 view (fits)
  float* outs = inpF32 + (long long)kN1 * kB;           // 6*kN1*64
  float* tail = outs + (long long)kNStep * kN1 * kB;
  int* counts = (int*)tail;                             // kN1
  int* poffsets = counts + kN1;                         // kN1+1
  int* cursor = poffsets + kN1 + 1;                     // kN1
  unsigned* packed = (unsigned*)(cursor + kN1);         // kPMax
  const size_t needed = (size_t)((char*)(packed + kPMax) - (char*)d_ws);

  lstm_kernel<<<kB, 256, 0, stream>>>(query_emb, w_ih, w_hh, b_ih, b_hh, r_set, hidden);
  attn_weight_kernel<<<kB, 128, 0, stream>>>(hidden, wl_w, wl_b, attnAll, weightAll);

  if (ws_size >= needed) {
    zero_kernel<<<(kN1 + 255) / 256, 256, 0, stream>>>(counts, colsumAll);
    hist_kernel<<<1024, 256, 0, stream>>>(nout, counts);
    scan_kernel<<<1, 1024, 0, stream>>>(counts, poffsets, cursor);
    fill_kernel<<<1024, 256, 0, stream>>>(packed);
    permute_kernel<<<1024, 256, 0, stream>>>(nin, nout, edge_type, cursor, packed);

    const int inp_threads = (kN1 + 1) * 16;
    for (int i = 0; i < kNStep; ++i) {
      float* out_i = outs + (long long)i * kN1 * kB;
      inp_kernel<<<(inp_threads + 255) / 256, 256, 0, stream>>>(
          attnAll, colsumAll, h_set, outs, inpH, i);
      gather_seg_kernel<<<kGatherBlocks, 256, 0, stream>>>(
          inpH, weightAll + i * kNRel2 * kB, packed, poffsets, out_i,
          colsumAll + i * kB);
    }
    score_kernel<<<(out_size + 255) / 256, 256, 0, stream>>>(
        outs + 5LL * kN1 * kB, colsumAll + 5 * kB, t_index, hr_inverse, lin_w, lin_b,
        out, out_size);
  } else {
    float* colsum = colsumAll;
    for (int i = 0; i < kNStep; ++i) {
      float* out_i = outs + (long long)i * kN1 * kB;
      inp_zero_kernel<<<2048, 256, 0, stream>>>(attnAll, h_set, outs, inpF32, out_i,
                                                colsum, i);
      scatter_kernel<<<4096, 256, 0, stream>>>(inpF32, weightAll + i * kNRel2 * kB,
                                               nin, nout, edge_type, out_i, colsum);
      normalize_kernel<<<2048, 256, 0, stream>>>(out_i, colsum);
    }
    score_kernel_norm<<<(out_size + 255) / 256, 256, 0, stream>>>(
        outs + 5LL * kN1 * kB, t_index, hr_inverse, lin_w, lin_b, out, out_size);
  }
}

// Round 6
// 669.698 us; speedup vs baseline: 5.6170x; 1.0690x over previous
//
#include <hip/hip_runtime.h>
#include <hip/hip_fp16.h>
#include <math.h>

namespace {

constexpr int kN1 = 20001;        // NUM_NODES + 1 (output rows)
constexpr int kNE = 1000000;      // NUM_EDGES
constexpr int kNStep = 6;
constexpr int kHid = 128;
constexpr int kB = 64;            // B_SET
constexpr int kNRel2 = 24;        // 2*NUM_REL
constexpr float kEps = 1e-10f;
constexpr unsigned kSent = (unsigned)kN1;     // sentinel src = zero row, etype 0
constexpr int kPMax = kNE + 8 * kN1;          // padded edge array bound
constexpr int kGatherBlocks = 2048;           // 8192 waves
constexpr int kNWaves = kGatherBlocks * 4;

__device__ __forceinline__ float sig(float x) { return 1.0f / (1.0f + expf(-x)); }

__device__ __forceinline__ float2 cvt2(unsigned u) {
  __half2 h = *reinterpret_cast<__half2*>(&u);
  return __half22float2(h);
}

// ---------------- LSTM front-end ----------------

// One-time: wt[k][j] (k<128 -> w_ih[j][k], k>=128 -> w_hh[j][k-128]), [256][512].
__global__ __launch_bounds__(256) void transpose_w_kernel(
    const float* __restrict__ w_ih, const float* __restrict__ w_hh,
    float* __restrict__ wt) {
  const int idx = blockIdx.x * 256 + threadIdx.x;
  if (idx < 256 * 512) {
    const int k = idx >> 9;
    const int j = idx & 511;
    wt[idx] = (k < 128) ? w_ih[j * kHid + k] : w_hh[j * kHid + (k - 128)];
  }
}

// 64 blocks x 512 threads; thread j computes gate row j with coalesced wt reads.
__global__ __launch_bounds__(512) void lstm_fast_kernel(
    const float* __restrict__ query_emb, const float* __restrict__ wt,
    const float* __restrict__ b_ih, const float* __restrict__ b_hh,
    const int* __restrict__ r_set, float* __restrict__ hidden /* (6,64,128) */) {
  const int b = blockIdx.x;
  const int tid = threadIdx.x;
  __shared__ float xh[256];     // [0..127]=x, [128..255]=h
  __shared__ float cst[kHid];
  __shared__ float gsm[512];
  const float bias = b_ih[tid] + b_hh[tid];
  const int q = r_set[b];
  if (tid < kHid) { cst[tid] = 0.f; xh[kHid + tid] = 0.f; }
  for (int s = 0; s < kNStep; ++s) {
    if (tid < kHid) xh[tid] = query_emb[((s < kNStep - 1) ? q : 12) * kHid + tid];
    __syncthreads();
    float acc = bias;
#pragma unroll 8
    for (int k = 0; k < 256; ++k) acc += xh[k] * wt[k * 512 + tid];
    gsm[tid] = acc;
    __syncthreads();
    if (tid < kHid) {
      const float ig = sig(gsm[tid]);
      const float fg = sig(gsm[kHid + tid]);
      const float gg = tanhf(gsm[2 * kHid + tid]);
      const float og = sig(gsm[3 * kHid + tid]);
      const float cn = fg * cst[tid] + ig * gg;
      cst[tid] = cn;
      const float hn = og * tanhf(cn);
      xh[kHid + tid] = hn;
      hidden[(s * kB + b) * kHid + tid] = hn;
    }
    __syncthreads();
  }
}

// Legacy LSTM (fallback path only).
__global__ __launch_bounds__(256) void lstm_kernel(
    const float* __restrict__ query_emb, const float* __restrict__ w_ih,
    const float* __restrict__ w_hh, const float* __restrict__ b_ih,
    const float* __restrict__ b_hh, const int* __restrict__ r_set,
    float* __restrict__ hidden) {
  const int b = blockIdx.x;
  const int tid = threadIdx.x;
  __shared__ float xs[kHid], hs[kHid], cs[kHid], gates[4 * kHid];
  if (tid < kHid) { hs[tid] = 0.f; cs[tid] = 0.f; }
  __syncthreads();
  for (int s = 0; s < kNStep; ++s) {
    const int q = (s < kNStep - 1) ? r_set[b] : 12;
    if (tid < kHid) xs[tid] = query_emb[q * kHid + tid];
    __syncthreads();
    for (int j = tid; j < 4 * kHid; j += blockDim.x) {
      const float* wi = &w_ih[j * kHid];
      const float* wh = &w_hh[j * kHid];
      float a = b_ih[j] + b_hh[j];
#pragma unroll 4
      for (int k = 0; k < kHid; ++k) a += xs[k] * wi[k] + hs[k] * wh[k];
      gates[j] = a;
    }
    __syncthreads();
    if (tid < kHid) {
      const float ig = sig(gates[tid]);
      const float fg = sig(gates[kHid + tid]);
      const float gg = tanhf(gates[2 * kHid + tid]);
      const float og = sig(gates[3 * kHid + tid]);
      const float cn = fg * cs[tid] + ig * gg;
      const float hn = og * tanhf(cn);
      cs[tid] = cn;
      hs[tid] = hn;
      hidden[(s * kB + b) * kHid + tid] = hn;
    }
    __syncthreads();
  }
}

__global__ __launch_bounds__(128) void attn_weight_kernel(
    const float* __restrict__ hidden, const float* __restrict__ wl_w,
    const float* __restrict__ wl_b, float* __restrict__ attnAll /* (6,6,64) */,
    float* __restrict__ weightAll /* (6,24,64) */) {
  const int b = blockIdx.x;
  const int tid = threadIdx.x;
  __shared__ float hsm[kNStep][kHid];
  __shared__ float G[kNStep][kNStep];
  __shared__ float logits[kNStep][kNRel2];
  for (int s = 0; s < kNStep; ++s) hsm[s][tid] = hidden[(s * kB + b) * kHid + tid];
  __syncthreads();
  if (tid < 36) {
    const int i = tid / 6, t = tid % 6;
    if (t <= i) {
      float acc = 0.f;
      for (int k = 0; k < kHid; ++k) acc += hsm[i][k] * hsm[t][k];
      G[i][t] = acc;
    }
  }
  for (int p = tid; p < kNStep * kNRel2; p += 128) {
    const int i = p / kNRel2, r = p % kNRel2;
    float acc = wl_b[r];
    for (int k = 0; k < kHid; ++k) acc += hsm[i][k] * wl_w[r * kHid + k];
    logits[i][r] = acc;
  }
  __syncthreads();
  if (tid < kNStep) {
    const int i = tid;
    float m = G[i][0];
    for (int t = 1; t <= i; ++t) m = fmaxf(m, G[i][t]);
    float ssum = 0.f;
    float ev[kNStep];
    for (int t = 0; t <= i; ++t) { ev[t] = expf(G[i][t] - m); ssum += ev[t]; }
    for (int t = 0; t <= i; ++t) attnAll[(i * kNStep + t) * kB + b] = ev[t] / ssum;
    float mw = logits[i][0];
    for (int r = 1; r < kNRel2; ++r) mw = fmaxf(mw, logits[i][r]);
    float sw = 0.f;
    float ew[kNRel2];
    for (int r = 0; r < kNRel2; ++r) { ew[r] = expf(logits[i][r] - mw); sw += ew[r]; }
    for (int r = 0; r < kNRel2; ++r) weightAll[(i * kNRel2 + r) * kB + b] = ew[r] / sw;
  }
}

// ---------------- edge preprocessing (once per launch) ----------------

__global__ __launch_bounds__(256) void zero_kernel(int* __restrict__ counts,
                                                   float* __restrict__ colsumAll) {
  const int i = blockIdx.x * blockDim.x + threadIdx.x;
  if (i < kN1) counts[i] = 0;
  if (i < kNStep * kB) colsumAll[i] = 0.f;
}

__global__ __launch_bounds__(256) void hist_kernel(const int* __restrict__ nout,
                                                   int* __restrict__ counts) {
  for (int e = blockIdx.x * blockDim.x + threadIdx.x; e < kNE;
       e += gridDim.x * blockDim.x)
    atomicAdd(&counts[nout[e]], 1);
}

// Exclusive scan of PADDED counts ((c+7)&~7). poffsets has kN1+1 entries.
__global__ __launch_bounds__(1024) void scan_kernel(const int* __restrict__ counts,
                                                    int* __restrict__ poffsets,
                                                    int* __restrict__ cursor) {
  __shared__ int part[1024];
  const int tid = threadIdx.x;
  const int chunk = (kN1 + 1023) / 1024;  // 20
  const int beg = tid * chunk;
  const int end = min(beg + chunk, kN1);
  int s = 0;
  for (int i = beg; i < end; ++i) s += (counts[i] + 7) & ~7;
  part[tid] = s;
  __syncthreads();
  for (int off = 1; off < 1024; off <<= 1) {
    const int v = (tid >= off) ? part[tid - off] : 0;
    __syncthreads();
    part[tid] += v;
    __syncthreads();
  }
  int run = part[tid] - s;  // exclusive prefix of this chunk
  for (int i = beg; i < end; ++i) {
    poffsets[i] = run;
    cursor[i] = run;
    run += (counts[i] + 7) & ~7;
  }
  if (tid == 1023) poffsets[kN1] = part[1023];
}

__global__ __launch_bounds__(256) void fill_kernel(unsigned* __restrict__ packed) {
  for (int i = blockIdx.x * blockDim.x + threadIdx.x; i < kPMax;
       i += gridDim.x * blockDim.x)
    packed[i] = kSent;
}

__global__ __launch_bounds__(256) void permute_kernel(
    const int* __restrict__ nin, const int* __restrict__ nout,
    const int* __restrict__ etype, int* __restrict__ cursor,
    unsigned* __restrict__ packed) {
  for (int e = blockIdx.x * blockDim.x + threadIdx.x; e < kNE;
       e += gridDim.x * blockDim.x) {
    const int d = nout[e];
    const int pos = atomicAdd(&cursor[d], 1);
    packed[pos] = (unsigned)nin[e] | ((unsigned)etype[e] << 15);
  }
}

// ---------------- per-step kernels ----------------

// One thread per (node, 4-col group). inp has kN1+1 rows; row kN1 = zero sentinel.
__global__ __launch_bounds__(256) void inp_kernel(
    const float* __restrict__ attnAll, const float* __restrict__ colsumAll,
    const int* __restrict__ h_set, const float* __restrict__ outs,
    __half* __restrict__ inp, int step) {
  __shared__ float coef[kNStep][kB];
  __shared__ int hsm[kB];
  const int tid = threadIdx.x;
  for (int j = tid; j < kNStep * kB; j += 256) {
    const int t = j >> 6, b = j & 63;
    float c = 0.f;
    if (t == 0)
      c = attnAll[(step * kNStep) * kB + b];
    else if (t <= step)
      c = attnAll[(step * kNStep + t) * kB + b] /
          fmaxf(colsumAll[(t - 1) * kB + b], kEps);
    coef[t][b] = c;
  }
  if (tid < kB) hsm[tid] = h_set[tid];
  __syncthreads();
  const int total = (kN1 + 1) * 16;
  for (int idx = blockIdx.x * blockDim.x + tid; idx < total;
       idx += gridDim.x * blockDim.x) {
    const int n = idx >> 4;
    const int cg = idx & 15;  // columns cg*4 .. cg*4+3
    float ax = 0.f, ay = 0.f, az = 0.f, aw = 0.f;
    if (n < kN1) {
      for (int t = 1; t <= step; ++t) {
        const float4 ct = *reinterpret_cast<const float4*>(&coef[t][cg * 4]);
        const float4 o = *reinterpret_cast<const float4*>(
            &outs[((long long)(t - 1) * kN1 + n) * kB + cg * 4]);
        ax += ct.x * o.x; ay += ct.y * o.y; az += ct.z * o.z; aw += ct.w * o.w;
      }
      const int c0 = cg * 4;
      if (hsm[c0 + 0] == n) ax += coef[0][c0 + 0];
      if (hsm[c0 + 1] == n) ay += coef[0][c0 + 1];
      if (hsm[c0 + 2] == n) az += coef[0][c0 + 2];
      if (hsm[c0 + 3] == n) aw += coef[0][c0 + 3];
    }
    __half2 h0 = __floats2half2_rn(ax, ay);
    __half2 h1 = __floats2half2_rn(az, aw);
    uint2 u;
    u.x = *reinterpret_cast<unsigned*>(&h0);
    u.y = *reinterpret_cast<unsigned*>(&h1);
    *reinterpret_cast<uint2*>(inp + (long long)idx * 4) = u;
  }
}

// Persistent-wave segmented SpMV, software-pipelined: 2 edge-groups (16 edges)
// per iteration, packed loads prefetched 2 groups ahead, both row-gathers
// issued before they're consumed -> ~3 memory chains in flight per wave.
__global__ __launch_bounds__(256) void gather_seg_kernel(
    const __half* __restrict__ inp /* (kN1+1, 64) */,
    const float* __restrict__ weight /* (24,64) */,
    const unsigned* __restrict__ packed, const int* __restrict__ poffsets,
    float* __restrict__ out, float* __restrict__ colsum) {
  __shared__ __align__(16) __half wsm[kNRel2 * kB];
  __shared__ float red[4][kB];
  const int tid = threadIdx.x;
  const int lane = tid & 63;
  const int wid = tid >> 6;
  const int g = lane >> 3;   // edge slot within group
  const int cb = lane & 7;   // 8-column block
  for (int j = tid; j < kNRel2 * kB; j += 256) wsm[j] = __float2half(weight[j]);
  __syncthreads();

  float csum[8] = {0.f, 0.f, 0.f, 0.f, 0.f, 0.f, 0.f, 0.f};
  float acc[8] = {0.f, 0.f, 0.f, 0.f, 0.f, 0.f, 0.f, 0.f};

  auto flushNode = [&](int node) {
#pragma unroll
    for (int j = 0; j < 8; ++j) {
      acc[j] += __shfl_xor(acc[j], 8);
      acc[j] += __shfl_xor(acc[j], 16);
      acc[j] += __shfl_xor(acc[j], 32);
    }
    if (g == 0) {
      *reinterpret_cast<float4*>(out + (long long)node * kB + cb * 8) =
          make_float4(acc[0], acc[1], acc[2], acc[3]);
      *reinterpret_cast<float4*>(out + (long long)node * kB + cb * 8 + 4) =
          make_float4(acc[4], acc[5], acc[6], acc[7]);
#pragma unroll
      for (int j = 0; j < 8; ++j) csum[j] += acc[j];
    }
#pragma unroll
    for (int j = 0; j < 8; ++j) acc[j] = 0.f;
  };

  const int wave = blockIdx.x * 4 + wid;
  const int P = poffsets[kN1];
  const int nG = P >> 3;
  const int chunkG = (nG + kNWaves - 1) / kNWaves;
  const int gbeg = wave * chunkG;
  if (gbeg < nG) {
    const int gend = min(gbeg + chunkG, nG);
    auto lb = [&](int x) {
      int lo = 0, hi = kN1;
      while (lo < hi) {
        const int mid = (lo + hi) >> 1;
        if (poffsets[mid] < x) lo = mid + 1; else hi = mid;
      }
      return lo;
    };
    const int nbeg = lb(gbeg * 8);
    const int nend = (gend >= nG) ? kN1 : lb(gend * 8);
    if (nbeg < nend) {
      int n = nbeg;
      int nextB = poffsets[n + 1];
      const int ebeg = poffsets[nbeg];
      const int eend = poffsets[nend];
      // pipeline prologue: packed + row loads for first two groups
      unsigned pA = (ebeg < eend) ? packed[ebeg + g] : kSent;
      unsigned pB = (ebeg + 8 < eend) ? packed[ebeg + 8 + g] : kSent;
      uint4 vA = *reinterpret_cast<const uint4*>(
          inp + (long long)(pA & 0x7fffu) * kB + cb * 8);
      uint4 vB = *reinterpret_cast<const uint4*>(
          inp + (long long)(pB & 0x7fffu) * kB + cb * 8);
      for (int ebase = ebeg; ebase < eend; ebase += 16) {
        const bool hasB = (ebase + 8) < eend;
        const int e2 = ebase + 16, e3 = ebase + 24;
        const unsigned pC = (e2 < eend) ? packed[e2 + g] : kSent;
        const unsigned pD = (e3 < eend) ? packed[e3 + g] : kSent;
        // group A
        while (ebase >= nextB) { flushNode(n); ++n; nextB = poffsets[n + 1]; }
        {
          const uint4 w4 =
              *reinterpret_cast<const uint4*>(wsm + (pA >> 15) * kB + cb * 8);
          const float2 v0 = cvt2(vA.x), v1 = cvt2(vA.y), v2 = cvt2(vA.z), v3 = cvt2(vA.w);
          const float2 w0 = cvt2(w4.x), w1 = cvt2(w4.y), w2 = cvt2(w4.z), w3 = cvt2(w4.w);
          acc[0] += v0.x * w0.x; acc[1] += v0.y * w0.y;
          acc[2] += v1.x * w1.x; acc[3] += v1.y * w1.y;
          acc[4] += v2.x * w2.x; acc[5] += v2.y * w2.y;
          acc[6] += v3.x * w3.x; acc[7] += v3.y * w3.y;
        }
        // group B
        if (hasB) {
          while (ebase + 8 >= nextB) { flushNode(n); ++n; nextB = poffsets[n + 1]; }
          const uint4 w4 =
              *reinterpret_cast<const uint4*>(wsm + (pB >> 15) * kB + cb * 8);
          const float2 v0 = cvt2(vB.x), v1 = cvt2(vB.y), v2 = cvt2(vB.z), v3 = cvt2(vB.w);
          const float2 w0 = cvt2(w4.x), w1 = cvt2(w4.y), w2 = cvt2(w4.z), w3 = cvt2(w4.w);
          acc[0] += v0.x * w0.x; acc[1] += v0.y * w0.y;
          acc[2] += v1.x * w1.x; acc[3] += v1.y * w1.y;
          acc[4] += v2.x * w2.x; acc[5] += v2.y * w2.y;
          acc[6] += v3.x * w3.x; acc[7] += v3.y * w3.y;
        }
        // rotate: issue next row-gathers (consumed next iteration)
        pA = pC; pB = pD;
        vA = *reinterpret_cast<const uint4*>(
            inp + (long long)(pC & 0x7fffu) * kB + cb * 8);
        vB = *reinterpret_cast<const uint4*>(
            inp + (long long)(pD & 0x7fffu) * kB + cb * 8);
      }
      while (n < nend) { flushNode(n); ++n; }
    }
  }
  // block-level colsum reduce -> one atomic round per block
  if (g == 0) {
#pragma unroll
    for (int j = 0; j < 8; ++j) red[wid][cb * 8 + j] = csum[j];
  }
  __syncthreads();
  if (wid == 0) {
    const float r = red[0][lane] + red[1][lane] + red[2][lane] + red[3][lane];
    unsafeAtomicAdd(&colsum[lane], r);
  }
}

__global__ __launch_bounds__(256) void score_kernel(
    const float* __restrict__ outLast, const float* __restrict__ colsumLast,
    const int* __restrict__ t_index, const int* __restrict__ hr_inverse,
    const float* __restrict__ lin_w, const float* __restrict__ lin_b,
    float* __restrict__ out, int n) {
  const int i = blockIdx.x * blockDim.x + threadIdx.x;
  if (i < n) {
    const int node = t_index[i];
    const int b = hr_inverse[i];
    const float v = outLast[(long long)node * kB + b] / fmaxf(colsumLast[b], kEps);
    out[i] = v * lin_w[0] + lin_b[0];
  }
}

// ---------------- fallback (float-atomic scatter) ----------------

__global__ __launch_bounds__(256) void inp_zero_kernel(
    const float* __restrict__ attnAll, const int* __restrict__ h_set,
    const float* __restrict__ outs, float* __restrict__ inp,
    float* __restrict__ out_next, float* __restrict__ colsum, int step) {
  const long long total = (long long)kN1 * kB;
  for (long long idx = (long long)blockIdx.x * blockDim.x + threadIdx.x; idx < total;
       idx += (long long)gridDim.x * blockDim.x) {
    const int b = (int)(idx & 63);
    const int n = (int)(idx >> 6);
    float acc = (h_set[b] == n) ? attnAll[(step * kNStep) * kB + b] : 0.f;
    for (int t = 1; t <= step; ++t)
      acc += attnAll[(step * kNStep + t) * kB + b] *
             outs[(long long)(t - 1) * kN1 * kB + idx];
    inp[idx] = acc;
    out_next[idx] = 0.f;
  }
  if (blockIdx.x == 0 && threadIdx.x < kB) colsum[threadIdx.x] = 0.f;
}

__global__ __launch_bounds__(256) void scatter_kernel(
    const float* __restrict__ inp, const float* __restrict__ weight,
    const int* __restrict__ nin, const int* __restrict__ nout,
    const int* __restrict__ etype, float* __restrict__ out,
    float* __restrict__ colsum) {
  const int lane = threadIdx.x & 63;
  const int wave = blockIdx.x * (blockDim.x >> 6) + (threadIdx.x >> 6);
  const int nwave = gridDim.x * (blockDim.x >> 6);
  __shared__ float wsm[kNRel2 * kB];
  for (int j = threadIdx.x; j < kNRel2 * kB; j += blockDim.x) wsm[j] = weight[j];
  __syncthreads();
  float csum = 0.f;
  for (int e = wave; e < kNE; e += nwave) {
    const float v = inp[(long long)nin[e] * kB + lane] * wsm[etype[e] * kB + lane];
    unsafeAtomicAdd(&out[(long long)nout[e] * kB + lane], v);
    csum += v;
  }
  unsafeAtomicAdd(&colsum[lane], csum);
}

__global__ __launch_bounds__(256) void normalize_kernel(
    float* __restrict__ out, const float* __restrict__ colsum) {
  const long long total = (long long)kN1 * kB;
  for (long long idx = (long long)blockIdx.x * blockDim.x + threadIdx.x; idx < total;
       idx += (long long)gridDim.x * blockDim.x)
    out[idx] /= fmaxf(colsum[idx & 63], kEps);
}

__global__ __launch_bounds__(256) void score_kernel_norm(
    const float* __restrict__ outLast, const int* __restrict__ t_index,
    const int* __restrict__ hr_inverse, const float* __restrict__ lin_w,
    const float* __restrict__ lin_b, float* __restrict__ out, int n) {
  const int i = blockIdx.x * blockDim.x + threadIdx.x;
  if (i < n) {
    out[i] = outLast[(long long)t_index[i] * kB + hr_inverse[i]] * lin_w[0] + lin_b[0];
  }
}

}  // namespace

extern "C" void kernel_launch(void* const* d_in, const int* in_sizes, int n_in,
                              void* d_out, int out_size, void* d_ws, size_t ws_size,
                              hipStream_t stream) {
  const float* query_emb = (const float*)d_in[0];
  const float* w_ih = (const float*)d_in[1];
  const float* w_hh = (const float*)d_in[2];
  const float* b_ih = (const float*)d_in[3];
  const float* b_hh = (const float*)d_in[4];
  const float* wl_w = (const float*)d_in[5];
  const float* wl_b = (const float*)d_in[6];
  const float* lin_w = (const float*)d_in[7];
  const float* lin_b = (const float*)d_in[8];
  const int* edge_index = (const int*)d_in[9];
  const int* edge_type = (const int*)d_in[10];
  const int* h_set = (const int*)d_in[11];
  const int* r_set = (const int*)d_in[12];
  const int* t_index = (const int*)d_in[13];
  const int* hr_inverse = (const int*)d_in[14];
  float* out = (float*)d_out;

  const int* nin = edge_index;
  const int* nout = edge_index + kNE;

  // ---- workspace layout ----
  float* ws = (float*)d_ws;
  float* hidden = ws;                                   // 6*64*128
  float* attnAll = hidden + kNStep * kB * kHid;         // 6*6*64
  float* weightAll = attnAll + kNStep * kNStep * kB;    // 6*24*64
  float* colsumAll = weightAll + kNStep * kNRel2 * kB;  // 6*64
  float* inpF32 = colsumAll + kNStep * kB;              // kN1*64 f32 slot
  __half* inpH = (__half*)inpF32;                       // (kN1+1)*64 fp16 view (fits)
  float* outs = inpF32 + (long long)kN1 * kB;           // 6*kN1*64
  float* tail = outs + (long long)kNStep * kN1 * kB;
  int* counts = (int*)tail;                             // kN1
  int* poffsets = counts + kN1;                         // kN1+1
  int* cursor = poffsets + kN1 + 1;                     // kN1
  unsigned* packed = (unsigned*)(cursor + kN1);         // kPMax
  float* wt = (float*)(packed + kPMax);                 // 256*512
  const size_t needed = (size_t)((char*)(wt + 256 * 512) - (char*)d_ws);

  if (ws_size >= needed) {
    transpose_w_kernel<<<512, 256, 0, stream>>>(w_ih, w_hh, wt);
    lstm_fast_kernel<<<kB, 512, 0, stream>>>(query_emb, wt, b_ih, b_hh, r_set, hidden);
    attn_weight_kernel<<<kB, 128, 0, stream>>>(hidden, wl_w, wl_b, attnAll, weightAll);

    zero_kernel<<<(kN1 + 255) / 256, 256, 0, stream>>>(counts, colsumAll);
    hist_kernel<<<1024, 256, 0, stream>>>(nout, counts);
    scan_kernel<<<1, 1024, 0, stream>>>(counts, poffsets, cursor);
    fill_kernel<<<1024, 256, 0, stream>>>(packed);
    permute_kernel<<<1024, 256, 0, stream>>>(nin, nout, edge_type, cursor, packed);

    const int inp_threads = (kN1 + 1) * 16;
    for (int i = 0; i < kNStep; ++i) {
      float* out_i = outs + (long long)i * kN1 * kB;
      inp_kernel<<<(inp_threads + 255) / 256, 256, 0, stream>>>(
          attnAll, colsumAll, h_set, outs, inpH, i);
      gather_seg_kernel<<<kGatherBlocks, 256, 0, stream>>>(
          inpH, weightAll + i * kNRel2 * kB, packed, poffsets, out_i,
          colsumAll + i * kB);
    }
    score_kernel<<<(out_size + 255) / 256, 256, 0, stream>>>(
        outs + 5LL * kN1 * kB, colsumAll + 5 * kB, t_index, hr_inverse, lin_w, lin_b,
        out, out_size);
  } else {
    lstm_kernel<<<kB, 256, 0, stream>>>(query_emb, w_ih, w_hh, b_ih, b_hh, r_set,
                                        hidden);
    attn_weight_kernel<<<kB, 128, 0, stream>>>(hidden, wl_w, wl_b, attnAll, weightAll);
    float* colsum = colsumAll;
    for (int i = 0; i < kNStep; ++i) {
      float* out_i = outs + (long long)i * kN1 * kB;
      inp_zero_kernel<<<2048, 256, 0, stream>>>(attnAll, h_set, outs, inpF32, out_i,
                                                colsum, i);
      scatter_kernel<<<4096, 256, 0, stream>>>(inpF32, weightAll + i * kNRel2 * kB,
                                               nin, nout, edge_type, out_i, colsum);
      normalize_kernel<<<2048, 256, 0, stream>>>(out_i, colsum);
    }
    score_kernel_norm<<<(out_size + 255) / 256, 256, 0, stream>>>(
        outs + 5LL * kN1 * kB, t_index, hr_inverse, lin_w, lin_b, out, out_size);
  }
}